// Round 7
// baseline (224.202 us; speedup 1.0000x reference)
//
#include <hip/hip_runtime.h>
#include <hip/hip_bf16.h>

#define NN 20000
#define FF 128
#define HH 256
#define EDIM 128
#define GG 64
#define NEDGE 320000
#define PSUB 16
#define CSTRIDE 64   // max in-degree slot count (mean 16, sigma 4 -> 64 is ~12 sigma)

typedef __attribute__((ext_vector_type(4))) float f4;
typedef __attribute__((ext_vector_type(4))) float f32x4;
typedef __attribute__((ext_vector_type(8))) short bf16x8;
typedef __attribute__((ext_vector_type(4))) unsigned short u16x4;
typedef __attribute__((ext_vector_type(4))) int i32x4;

__device__ inline float wsum(float v) {
#pragma unroll
    for (int m = 32; m >= 1; m >>= 1) v += __shfl_xor(v, m, 64);
    return v;
}

__device__ inline unsigned short f2b(float f) {
    union { float f; unsigned u; } x; x.f = f;
    unsigned r = x.u + 0x7fffu + ((x.u >> 16) & 1u);   // RNE
    return (unsigned short)(r >> 16);
}
__device__ inline float b2f(unsigned short u) {
    union { unsigned u; float f; } x; x.u = ((unsigned)u) << 16;
    return x.f;
}

// ---------------- adjacency build: degree count + fixed-stride slot fill ----------------
__global__ void k_build(const int* __restrict__ src, const int* __restrict__ dst,
                        int* __restrict__ cnt, int* __restrict__ col, int ne) {
    int e = blockIdx.x * blockDim.x + threadIdx.x;
    if (e < ne) {
        int d = dst[e];
        int pos = atomicAdd(&cnt[d], 1);
        if (pos < CSTRIDE) col[(size_t)d * CSTRIDE + pos] = src[e];
    }
}

// ---------------- prep: x -> bf16 (2500), zero cnt (20), weight transpose via LDS (56) ----
// transpose tiles: enc 8 (2k x 4n), w1/w2/w3 16 each (4k x 4n)
__global__ void k_prep(const float* __restrict__ x, unsigned short* __restrict__ xb,
                       const float* __restrict__ W0, const float* __restrict__ W1,
                       const float* __restrict__ W2, const float* __restrict__ W3,
                       unsigned short* __restrict__ T0, unsigned short* __restrict__ T1,
                       unsigned short* __restrict__ T2, unsigned short* __restrict__ T3,
                       int* __restrict__ cnt) {
    int b = blockIdx.x, tid = threadIdx.x;
    if (b < 2500) {
        int t = b * 256 + tid;           // n4 = 20000*128/4 = 640000
        f4 v = ((const f4*)x)[t];
        u16x4 o = { f2b(v[0]), f2b(v[1]), f2b(v[2]), f2b(v[3]) };
        ((u16x4*)xb)[t] = o;
        return;
    }
    if (b < 2520) {
        int t = (b - 2500) * 256 + tid;
        if (t < NN / 4) ((i32x4*)cnt)[t] = (i32x4){0, 0, 0, 0};
        return;
    }
    // weight transpose: W[k][n] fp32 -> T[n][k] bf16, 64x64 tiles
    const float* W; unsigned short* T; int K, tt;
    if (b < 2528)      { W = W0; T = T0; K = 128; tt = b - 2520; }
    else if (b < 2544) { W = W1; T = T1; K = 256; tt = b - 2528; }
    else if (b < 2560) { W = W2; T = T2; K = 256; tt = b - 2544; }
    else               { W = W3; T = T3; K = 256; tt = b - 2560; }
    int ktiles = K / 64;
    int kt = tt % ktiles, nt = tt / ktiles;
    int k0 = kt * 64, n0 = nt * 64;
    __shared__ unsigned short ldsT[64][65];   // [n][k]
    int rn = (tid & 15) * 4, rk = tid >> 4;   // read: rows k0+rk+16i, cols n0+rn..rn+4
#pragma unroll
    for (int i = 0; i < 4; i++) {
        int k = rk + 16 * i;
        f4 v = *(const f4*)(W + (size_t)(k0 + k) * 256 + n0 + rn);
#pragma unroll
        for (int j = 0; j < 4; j++) ldsT[rn + j][k] = f2b(v[j]);
    }
    __syncthreads();
    int wn = tid >> 2, kseg = (tid & 3) * 16; // write: row n0+wn, shorts k0+kseg..+16
#pragma unroll
    for (int q = 0; q < 4; q++) {
        u16x4 o = { ldsT[wn][kseg + q * 4 + 0], ldsT[wn][kseg + q * 4 + 1],
                    ldsT[wn][kseg + q * 4 + 2], ldsT[wn][kseg + q * 4 + 3] };
        *(u16x4*)(T + (size_t)(n0 + wn) * K + k0 + kseg + q * 4) = o;
    }
}

// ---------------- bf16 MFMA GEMM, no-LDS (C = X @ W via Wt[n][k], swapped-operand) ------
// W panel (<=128 KB) is L2-resident and shared by all blocks -> read fragments straight
// from global; no pack loop, no __syncthreads, fully-unrolled K loop pipelines freely.
// grid (4, ceil(M/128)); block = 4 waves; wave = 32 rows x 64 cols (2x4 frags).
template<int K>
__global__ __launch_bounds__(256) void bgemm(const unsigned short* __restrict__ Xb,
                                             const unsigned short* __restrict__ Wt,
                                             unsigned short* __restrict__ C, int M) {
    constexpr int KSTEPS = K / 32;
    int tid = threadIdx.x;
    int n0 = blockIdx.x * 64;
    int wave = tid >> 6, lane = tid & 63;
    int lmod = lane & 15, ldiv = lane >> 4;
    int mbase = blockIdx.y * 128 + wave * 32;
    const unsigned short* wbase = Wt + (size_t)(n0 + lmod) * K + ldiv * 8;
    f32x4 acc[2][4] = {};
#pragma unroll
    for (int ks = 0; ks < KSTEPS; ks++) {
        int k0 = ks * 32 + ldiv * 8;
        bf16x8 xf[2], wf[4];
#pragma unroll
        for (int mf = 0; mf < 2; mf++) {
            int row = mbase + mf * 16 + lmod;
            row = min(row, M - 1);
            xf[mf] = *(const bf16x8*)(Xb + (size_t)row * K + k0);
        }
#pragma unroll
        for (int nf = 0; nf < 4; nf++) {
            wf[nf] = *(const bf16x8*)(wbase + (size_t)nf * 16 * K + ks * 32);
        }
#pragma unroll
        for (int mf = 0; mf < 2; mf++) {
#pragma unroll
            for (int nf = 0; nf < 4; nf++) {
                acc[mf][nf] = __builtin_amdgcn_mfma_f32_16x16x32_bf16(
                    wf[nf], xf[mf], acc[mf][nf], 0, 0, 0);
            }
        }
    }
#pragma unroll
    for (int mf = 0; mf < 2; mf++) {
        int m = mbase + mf * 16 + lmod;
        if (m < M) {
#pragma unroll
            for (int nf = 0; nf < 4; nf++) {
                int n = n0 + nf * 16 + ldiv * 4;
                u16x4 o = { f2b(acc[mf][nf][0]), f2b(acc[mf][nf][1]),
                            f2b(acc[mf][nf][2]), f2b(acc[mf][nf][3]) };
                *(u16x4*)(C + (size_t)m * 256 + n) = o;
            }
        }
    }
}

// ---------------- encoder: h = relu(LN(T + b)), one wave per row ----------------
__global__ void k_encln(const unsigned short* __restrict__ T, const float* __restrict__ b,
                        const float* __restrict__ gam, const float* __restrict__ bet,
                        unsigned short* __restrict__ out, int n) {
    int wid = (blockIdx.x * blockDim.x + threadIdx.x) >> 6;
    int lane = threadIdx.x & 63;
    if (wid >= n) return;
    u16x4 tv = ((const u16x4*)(T + (size_t)wid * HH))[lane];
    f4 bb = ((const f4*)b)[lane];
    f4 v = { b2f(tv[0]) + bb[0], b2f(tv[1]) + bb[1], b2f(tv[2]) + bb[2], b2f(tv[3]) + bb[3] };
    float s = wsum(v[0] + v[1] + v[2] + v[3]);
    float mean = s * (1.0f / HH);
    f4 d = v - mean;
    float ss = wsum(d[0] * d[0] + d[1] * d[1] + d[2] * d[2] + d[3] * d[3]);
    float rs = rsqrtf(ss * (1.0f / HH) + 1e-5f);
    f4 gv = ((const f4*)gam)[lane], bv = ((const f4*)bet)[lane];
    f4 o = d * rs * gv + bv;
    u16x4 ov;
#pragma unroll
    for (int i = 0; i < 4; i++) ov[i] = f2b(fmaxf(o[i], 0.0f));
    ((u16x4*)(out + (size_t)wid * HH))[lane] = ov;
}

// ------------- GCN agg + bias + LN + relu (+ residual) (+ fused attention logit) -------------
__global__ void k_aggln(const unsigned short* __restrict__ T, const int* __restrict__ cnt,
                        const int* __restrict__ col,
                        const float* __restrict__ b, const float* __restrict__ gam,
                        const float* __restrict__ bet, const unsigned short* __restrict__ resid,
                        unsigned short* __restrict__ out,
                        const float* __restrict__ aw, const float* __restrict__ ab,
                        float* __restrict__ elog, int n) {
    int wid = (blockIdx.x * blockDim.x + threadIdx.x) >> 6;
    int lane = threadIdx.x & 63;
    if (wid >= n) return;
    int deg = min(cnt[wid], CSTRIDE);
    const int* cr = col + (size_t)wid * CSTRIDE;
    f4 a0 = {0.f,0.f,0.f,0.f}, a1 = {0.f,0.f,0.f,0.f};
    f4 a2 = {0.f,0.f,0.f,0.f}, a3 = {0.f,0.f,0.f,0.f};
    int e = 0;
    for (; e + 7 < deg; e += 8) {          // 8 independent row loads in flight
        i32x4 cA = *(const i32x4*)(cr + e);
        i32x4 cB = *(const i32x4*)(cr + e + 4);
        u16x4 r0 = ((const u16x4*)(T + (size_t)cA[0] * HH))[lane];
        u16x4 r1 = ((const u16x4*)(T + (size_t)cA[1] * HH))[lane];
        u16x4 r2 = ((const u16x4*)(T + (size_t)cA[2] * HH))[lane];
        u16x4 r3 = ((const u16x4*)(T + (size_t)cA[3] * HH))[lane];
        u16x4 r4 = ((const u16x4*)(T + (size_t)cB[0] * HH))[lane];
        u16x4 r5 = ((const u16x4*)(T + (size_t)cB[1] * HH))[lane];
        u16x4 r6 = ((const u16x4*)(T + (size_t)cB[2] * HH))[lane];
        u16x4 r7 = ((const u16x4*)(T + (size_t)cB[3] * HH))[lane];
        float w0 = rsqrtf((float)(cnt[cA[0]] + 1));
        float w1 = rsqrtf((float)(cnt[cA[1]] + 1));
        float w2 = rsqrtf((float)(cnt[cA[2]] + 1));
        float w3 = rsqrtf((float)(cnt[cA[3]] + 1));
        float w4 = rsqrtf((float)(cnt[cB[0]] + 1));
        float w5 = rsqrtf((float)(cnt[cB[1]] + 1));
        float w6 = rsqrtf((float)(cnt[cB[2]] + 1));
        float w7 = rsqrtf((float)(cnt[cB[3]] + 1));
#pragma unroll
        for (int i = 0; i < 4; i++) {
            a0[i] = fmaf(w0, b2f(r0[i]), a0[i]);
            a1[i] = fmaf(w1, b2f(r1[i]), a1[i]);
            a2[i] = fmaf(w2, b2f(r2[i]), a2[i]);
            a3[i] = fmaf(w3, b2f(r3[i]), a3[i]);
            a0[i] = fmaf(w4, b2f(r4[i]), a0[i]);
            a1[i] = fmaf(w5, b2f(r5[i]), a1[i]);
            a2[i] = fmaf(w6, b2f(r6[i]), a2[i]);
            a3[i] = fmaf(w7, b2f(r7[i]), a3[i]);
        }
    }
    for (; e + 3 < deg; e += 4) {
        i32x4 c4 = *(const i32x4*)(cr + e);
        float w0 = rsqrtf((float)(cnt[c4[0]] + 1));
        float w1 = rsqrtf((float)(cnt[c4[1]] + 1));
        float w2 = rsqrtf((float)(cnt[c4[2]] + 1));
        float w3 = rsqrtf((float)(cnt[c4[3]] + 1));
        u16x4 r0 = ((const u16x4*)(T + (size_t)c4[0] * HH))[lane];
        u16x4 r1 = ((const u16x4*)(T + (size_t)c4[1] * HH))[lane];
        u16x4 r2 = ((const u16x4*)(T + (size_t)c4[2] * HH))[lane];
        u16x4 r3 = ((const u16x4*)(T + (size_t)c4[3] * HH))[lane];
#pragma unroll
        for (int i = 0; i < 4; i++) {
            a0[i] = fmaf(w0, b2f(r0[i]), a0[i]);
            a1[i] = fmaf(w1, b2f(r1[i]), a1[i]);
            a2[i] = fmaf(w2, b2f(r2[i]), a2[i]);
            a3[i] = fmaf(w3, b2f(r3[i]), a3[i]);
        }
    }
    for (; e < deg; e++) {
        int s0 = cr[e];
        float w0 = rsqrtf((float)(cnt[s0] + 1));
        u16x4 r0 = ((const u16x4*)(T + (size_t)s0 * HH))[lane];
#pragma unroll
        for (int i = 0; i < 4; i++) a0[i] = fmaf(w0, b2f(r0[i]), a0[i]);
    }
    float di = rsqrtf((float)(deg + 1));
    u16x4 sv = ((const u16x4*)(T + (size_t)wid * HH))[lane];
    f4 bb = ((const f4*)b)[lane];
    f4 v;
#pragma unroll
    for (int i = 0; i < 4; i++)
        v[i] = di * (a0[i] + a1[i] + a2[i] + a3[i]) + (di * di) * b2f(sv[i]) + bb[i];
    float s = wsum(v[0] + v[1] + v[2] + v[3]);
    float mean = s * (1.0f / HH);
    f4 d = v - mean;
    float ss = wsum(d[0] * d[0] + d[1] * d[1] + d[2] * d[2] + d[3] * d[3]);
    float rs = rsqrtf(ss * (1.0f / HH) + 1e-5f);
    f4 gv = ((const f4*)gam)[lane], bv = ((const f4*)bet)[lane];
    f4 o = d * rs * gv + bv;
#pragma unroll
    for (int i = 0; i < 4; i++) o[i] = fmaxf(o[i], 0.0f);
    if (resid != nullptr) {
        u16x4 rv = ((const u16x4*)(resid + (size_t)wid * HH))[lane];
#pragma unroll
        for (int i = 0; i < 4; i++) o[i] += b2f(rv[i]);
    }
    u16x4 ov;
#pragma unroll
    for (int i = 0; i < 4; i++) ov[i] = f2b(o[i]);
    ((u16x4*)(out + (size_t)wid * HH))[lane] = ov;
    if (elog != nullptr) {   // fused attention logit on the stored (bf16) x3 values
        f4 wv = ((const f4*)aw)[lane];
        float dotv = wsum(b2f(ov[0]) * wv[0] + b2f(ov[1]) * wv[1] +
                          b2f(ov[2]) * wv[2] + b2f(ov[3]) * wv[3]);
        if (lane == 0) elog[wid] = expf(tanhf(dotv + ab[0]));
    }
}

// ---------------- pooling: partial weighted feature sums + partial elog sums ----------------
__device__ inline int lbound(const int* __restrict__ arr, int n, int key) {
    int lo = 0, hi = n;
    while (lo < hi) {
        int mid = (lo + hi) >> 1;
        if (arr[mid] < key) lo = mid + 1; else hi = mid;
    }
    return lo;
}

__global__ __launch_bounds__(256) void k_pool(const unsigned short* __restrict__ x3,
                                              const float* __restrict__ elog,
                                              const int* __restrict__ batch,
                                              float* __restrict__ partial,
                                              float* __restrict__ esum, int n) {
    int g = blockIdx.y, s = blockIdx.x, j = threadIdx.x;
    __shared__ int slo, shi;
    if (j == 0) { slo = lbound(batch, n, g); shi = lbound(batch, n, g + 1); }
    __syncthreads();
    int lo = slo, hi = shi;
    float a0 = 0.f, a1 = 0.f;
    int i = lo + s;
    for (; i + PSUB < hi; i += 2 * PSUB) {
        a0 += elog[i] * b2f(x3[(size_t)i * HH + j]);
        a1 += elog[i + PSUB] * b2f(x3[(size_t)(i + PSUB) * HH + j]);
    }
    if (i < hi) a0 += elog[i] * b2f(x3[(size_t)i * HH + j]);
    partial[(size_t)(g * PSUB + s) * HH + j] = a0 + a1;
    // per-slice elog sum (wave 0 only): rows i = lo + s + t*PSUB
    if (j < 64) {
        float es = 0.f;
        for (int t = j; (size_t)lo + s + (size_t)t * PSUB < (size_t)hi; t += 64)
            es += elog[lo + s + t * PSUB];
        es = wsum(es);
        if (j == 0) esum[g * PSUB + s] = es;
    }
}

// ---------------- tail: global elog sum + partial reduce + MLP + LN + project + L2 ----------------
__global__ __launch_bounds__(256) void k_tail(
    const float* __restrict__ partial, const float* __restrict__ esum,
    const float* __restrict__ pw1, const float* __restrict__ pb1,
    const float* __restrict__ pg, const float* __restrict__ pbe,
    const float* __restrict__ pw2, const float* __restrict__ pb2,
    float* __restrict__ out) {
    __shared__ float pl[256];
    __shared__ float ps[256];
    __shared__ float red[256];
    __shared__ float os[128];
    int g = blockIdx.x, j = threadIdx.x;
    float t = esum[j] + esum[j + 256] + esum[j + 512] + esum[j + 768];
    red[j] = t;
    __syncthreads();
    for (int s = 128; s > 0; s >>= 1) {
        if (j < s) red[j] += red[j + s];
        __syncthreads();
    }
    float inv = 1.0f / red[0];
    __syncthreads();
    float acc = 0.f;
#pragma unroll
    for (int s = 0; s < PSUB; s++) acc += partial[(size_t)(g * PSUB + s) * HH + j];
    pl[j] = acc * inv;
    __syncthreads();
    float q = pb1[j];
#pragma unroll 8
    for (int k = 0; k < 256; k++) q = fmaf(pl[k], pw1[k * 256 + j], q);
    red[j] = q;
    __syncthreads();
    for (int s = 128; s > 0; s >>= 1) {
        if (j < s) red[j] += red[j + s];
        __syncthreads();
    }
    float mean = red[0] * (1.0f / 256.0f);
    __syncthreads();
    float d = q - mean;
    red[j] = d * d;
    __syncthreads();
    for (int s = 128; s > 0; s >>= 1) {
        if (j < s) red[j] += red[j + s];
        __syncthreads();
    }
    float var = red[0] * (1.0f / 256.0f);
    __syncthreads();
    float p = fmaxf(d * rsqrtf(var + 1e-5f) * pg[j] + pbe[j], 0.0f);
    ps[j] = p;
    __syncthreads();
    if (j < 128) {
        float o = pb2[j];
#pragma unroll 8
        for (int k = 0; k < 256; k++) o = fmaf(ps[k], pw2[k * 128 + j], o);
        os[j] = o;
    }
    __syncthreads();
    float val = (j < 128) ? os[j] * os[j] : 0.f;
    red[j] = val;
    __syncthreads();
    for (int s = 128; s > 0; s >>= 1) {
        if (j < s) red[j] += red[j + s];
        __syncthreads();
    }
    float nrm = fmaxf(sqrtf(red[0]), 1e-12f);
    if (j < 128) out[g * 128 + j] = os[j] / nrm;
}

// ---------------- host ----------------
extern "C" void kernel_launch(void* const* d_in, const int* in_sizes, int n_in,
                              void* d_out, int out_size, void* d_ws, size_t ws_size,
                              hipStream_t stream) {
    const float* x      = (const float*)d_in[0];
    const int*   ei     = (const int*)d_in[1];
    const int*   batch  = (const int*)d_in[2];
    const float* enc_w  = (const float*)d_in[3];
    const float* enc_b  = (const float*)d_in[4];
    const float* enc_g  = (const float*)d_in[5];
    const float* enc_be = (const float*)d_in[6];
    const float* w1 = (const float*)d_in[7],  *b1 = (const float*)d_in[8];
    const float* g1 = (const float*)d_in[9],  *be1 = (const float*)d_in[10];
    const float* w2 = (const float*)d_in[11], *b2 = (const float*)d_in[12];
    const float* g2 = (const float*)d_in[13], *be2 = (const float*)d_in[14];
    const float* w3 = (const float*)d_in[15], *b3 = (const float*)d_in[16];
    const float* g3 = (const float*)d_in[17], *be3 = (const float*)d_in[18];
    const float* attn_w = (const float*)d_in[19], *attn_b = (const float*)d_in[20];
    const float* pw1 = (const float*)d_in[21], *pb1 = (const float*)d_in[22];
    const float* pg  = (const float*)d_in[23], *pbe = (const float*)d_in[24];
    const float* pw2 = (const float*)d_in[25], *pb2 = (const float*)d_in[26];
    float* out = (float*)d_out;

    const int* src = ei;
    const int* dst = ei + NEDGE;

    // bf16 region
    unsigned short* us = (unsigned short*)d_ws;
    unsigned short* Tb = us;                              // [NN,HH]
    unsigned short* Pb = Tb + (size_t)NN * HH;            // [NN,HH]
    unsigned short* Qb = Pb + (size_t)NN * HH;            // [NN,HH]
    unsigned short* xb = Qb + (size_t)NN * HH;            // [NN,FF]
    unsigned short* wte = xb + (size_t)NN * FF;           // [256*128]
    unsigned short* wt1 = wte + 256 * 128;                // [256*256]
    unsigned short* wt2 = wt1 + 256 * 256;
    unsigned short* wt3 = wt2 + 256 * 256;
    // fp32/int region (16B-aligned by construction)
    float* fp = (float*)(wt3 + 256 * 256);
    float* elog    = fp;                                  // [NN]
    float* partial = elog + NN;                           // [GG*PSUB*HH]
    float* esum    = partial + (size_t)GG * PSUB * HH;    // [GG*PSUB]
    int* cnt = (int*)(esum + GG * PSUB);                  // [NN]
    int* col = cnt + NN;                                  // [NN*CSTRIDE]

    // prep (also zeroes cnt) must complete before k_build's atomics
    k_prep<<<2576, 256, 0, stream>>>(x, xb, enc_w, w1, w2, w3, wte, wt1, wt2, wt3, cnt);
    k_build<<<(NEDGE + 255) / 256, 256, 0, stream>>>(src, dst, cnt, col, NEDGE);

    dim3 gg(4, 157);   // 628 blocks, 128-row tiles, no-LDS
    // encoder
    bgemm<128><<<gg, 256, 0, stream>>>(xb, wte, Tb, NN);
    k_encln<<<(NN + 3) / 4, 256, 0, stream>>>(Tb, enc_b, enc_g, enc_be, Pb, NN);
    // layer 1: h=Pb -> T -> x1=Qb
    bgemm<256><<<gg, 256, 0, stream>>>(Pb, wt1, Tb, NN);
    k_aggln<<<(NN + 3) / 4, 256, 0, stream>>>(Tb, cnt, col, b1, g1, be1, nullptr, Qb,
                                              nullptr, nullptr, nullptr, NN);
    // layer 2: x1=Qb -> T -> x2=Pb (resid Qb)
    bgemm<256><<<gg, 256, 0, stream>>>(Qb, wt2, Tb, NN);
    k_aggln<<<(NN + 3) / 4, 256, 0, stream>>>(Tb, cnt, col, b2, g2, be2, Qb, Pb,
                                              nullptr, nullptr, nullptr, NN);
    // layer 3: x2=Pb -> T -> x3=Qb (resid Pb), fused attention logits
    bgemm<256><<<gg, 256, 0, stream>>>(Pb, wt3, Tb, NN);
    k_aggln<<<(NN + 3) / 4, 256, 0, stream>>>(Tb, cnt, col, b3, g3, be3, Pb, Qb,
                                              attn_w, attn_b, elog, NN);
    // pooling + tail
    k_pool<<<dim3(PSUB, GG), 256, 0, stream>>>(Qb, elog, batch, partial, esum, NN);
    k_tail<<<GG, 256, 0, stream>>>(partial, esum, pw1, pb1, pg, pbe, pw2, pb2, out);
}

// Round 8
// 206.900 us; speedup vs baseline: 1.0836x; 1.0836x over previous
//
#include <hip/hip_runtime.h>
#include <hip/hip_bf16.h>

#define NN 20000
#define FF 128
#define HH 256
#define EDIM 128
#define GG 64
#define NEDGE 320000
#define PSUB 16
#define CSTRIDE 64   // max in-degree slot count (mean 16, sigma 4 -> 64 is ~12 sigma)

typedef __attribute__((ext_vector_type(4))) float f4;
typedef __attribute__((ext_vector_type(4))) float f32x4;
typedef __attribute__((ext_vector_type(8))) short bf16x8;
typedef __attribute__((ext_vector_type(4))) unsigned short u16x4;
typedef __attribute__((ext_vector_type(4))) int i32x4;

__device__ inline float wsum(float v) {
#pragma unroll
    for (int m = 32; m >= 1; m >>= 1) v += __shfl_xor(v, m, 64);
    return v;
}

__device__ inline unsigned short f2b(float f) {
    union { float f; unsigned u; } x; x.f = f;
    unsigned r = x.u + 0x7fffu + ((x.u >> 16) & 1u);   // RNE
    return (unsigned short)(r >> 16);
}
__device__ inline float b2f(unsigned short u) {
    union { unsigned u; float f; } x; x.u = ((unsigned)u) << 16;
    return x.f;
}

// ---------------- adjacency build: degree count + fixed-stride slot fill ----------------
__global__ void k_build(const int* __restrict__ src, const int* __restrict__ dst,
                        int* __restrict__ cnt, int* __restrict__ col, int ne) {
    int e = blockIdx.x * blockDim.x + threadIdx.x;
    if (e < ne) {
        int d = dst[e];
        int pos = atomicAdd(&cnt[d], 1);
        if (pos < CSTRIDE) col[(size_t)d * CSTRIDE + pos] = src[e];
    }
}

// ---------------- prep: x -> bf16 (2500), zero cnt (20), weight transpose via LDS (56) ----
__global__ void k_prep(const float* __restrict__ x, unsigned short* __restrict__ xb,
                       const float* __restrict__ W0, const float* __restrict__ W1,
                       const float* __restrict__ W2, const float* __restrict__ W3,
                       unsigned short* __restrict__ T0, unsigned short* __restrict__ T1,
                       unsigned short* __restrict__ T2, unsigned short* __restrict__ T3,
                       int* __restrict__ cnt) {
    int b = blockIdx.x, tid = threadIdx.x;
    if (b < 2500) {
        int t = b * 256 + tid;           // n4 = 20000*128/4 = 640000
        f4 v = ((const f4*)x)[t];
        u16x4 o = { f2b(v[0]), f2b(v[1]), f2b(v[2]), f2b(v[3]) };
        ((u16x4*)xb)[t] = o;
        return;
    }
    if (b < 2520) {
        int t = (b - 2500) * 256 + tid;
        if (t < NN / 4) ((i32x4*)cnt)[t] = (i32x4){0, 0, 0, 0};
        return;
    }
    // weight transpose: W[k][n] fp32 -> T[n][k] bf16, 64x64 tiles
    const float* W; unsigned short* T; int K, tt;
    if (b < 2528)      { W = W0; T = T0; K = 128; tt = b - 2520; }
    else if (b < 2544) { W = W1; T = T1; K = 256; tt = b - 2528; }
    else if (b < 2560) { W = W2; T = T2; K = 256; tt = b - 2544; }
    else               { W = W3; T = T3; K = 256; tt = b - 2560; }
    int ktiles = K / 64;
    int kt = tt % ktiles, nt = tt / ktiles;
    int k0 = kt * 64, n0 = nt * 64;
    __shared__ unsigned short ldsT[64][65];   // [n][k]
    int rn = (tid & 15) * 4, rk = tid >> 4;
#pragma unroll
    for (int i = 0; i < 4; i++) {
        int k = rk + 16 * i;
        f4 v = *(const f4*)(W + (size_t)(k0 + k) * 256 + n0 + rn);
#pragma unroll
        for (int j = 0; j < 4; j++) ldsT[rn + j][k] = f2b(v[j]);
    }
    __syncthreads();
    int wn = tid >> 2, kseg = (tid & 3) * 16;
#pragma unroll
    for (int q = 0; q < 4; q++) {
        u16x4 o = { ldsT[wn][kseg + q * 4 + 0], ldsT[wn][kseg + q * 4 + 1],
                    ldsT[wn][kseg + q * 4 + 2], ldsT[wn][kseg + q * 4 + 3] };
        *(u16x4*)(T + (size_t)(n0 + wn) * K + k0 + kseg + q * 4) = o;
    }
}

// ---------------- bf16 MFMA GEMM with LDS W panel (layers 1-3) ----------------
// grid (4, 157) = 628 blocks; block = 4 waves; wave = 32 rows x 64 cols (2x4 frags).
#define GEMM_NWG 628
template<int K>
__global__ __launch_bounds__(256) void bgemm(const unsigned short* __restrict__ Xb,
                                             const unsigned short* __restrict__ Wt,
                                             unsigned short* __restrict__ C, int M) {
    constexpr int KSTEPS = K / 32;
    __shared__ unsigned short Wl[KSTEPS * 4 * 64 * 8];
    int tid = threadIdx.x;
    int orig = blockIdx.y * 4 + blockIdx.x;
    int xcd = orig & 7, rest = orig >> 3;
    constexpr int q = GEMM_NWG >> 3, r = GEMM_NWG & 7;
    int wg = (xcd < r ? xcd * (q + 1) : r * (q + 1) + (xcd - r) * q) + rest;
    int m0 = wg >> 2;
    int n0 = (wg & 3) * 64;
    for (int c = tid; c < KSTEPS * 4 * 64; c += 256) {
        int lc = c & 63;
        int nf = (c >> 6) & 3;
        int ks = c >> 8;
        int n = n0 + nf * 16 + (lc & 15);
        int k = ks * 32 + (lc >> 4) * 8;
        bf16x8 v = *(const bf16x8*)(Wt + (size_t)n * K + k);
        *(bf16x8*)(Wl + (size_t)c * 8) = v;
    }
    __syncthreads();
    int wave = tid >> 6, lane = tid & 63;
    int lmod = lane & 15, ldiv = lane >> 4;
    int mbase = m0 * 128 + wave * 32;
    f32x4 acc[2][4] = {};
#pragma unroll
    for (int ks = 0; ks < KSTEPS; ks++) {
        int k0 = ks * 32 + ldiv * 8;
        bf16x8 xf[2], wf[4];
#pragma unroll
        for (int mf = 0; mf < 2; mf++) {
            int row = mbase + mf * 16 + lmod;
            row = min(row, M - 1);
            xf[mf] = *(const bf16x8*)(Xb + (size_t)row * K + k0);
        }
#pragma unroll
        for (int nf = 0; nf < 4; nf++) {
            wf[nf] = *(const bf16x8*)(Wl + ((size_t)(ks * 4 + nf) * 64 + lane) * 8);
        }
#pragma unroll
        for (int mf = 0; mf < 2; mf++) {
#pragma unroll
            for (int nf = 0; nf < 4; nf++) {
                acc[mf][nf] = __builtin_amdgcn_mfma_f32_16x16x32_bf16(
                    wf[nf], xf[mf], acc[mf][nf], 0, 0, 0);
            }
        }
    }
#pragma unroll
    for (int mf = 0; mf < 2; mf++) {
        int m = mbase + mf * 16 + lmod;
        if (m < M) {
#pragma unroll
            for (int nf = 0; nf < 4; nf++) {
                int n = n0 + nf * 16 + ldiv * 4;
                u16x4 o = { f2b(acc[mf][nf][0]), f2b(acc[mf][nf][1]),
                            f2b(acc[mf][nf][2]), f2b(acc[mf][nf][3]) };
                *(u16x4*)(C + (size_t)m * 256 + n) = o;
            }
        }
    }
}

// ---------------- fused encoder: h = relu(LN(x @ enc_w + b)) in one kernel ----------------
// Full-width blocks: 4 waves x 16 rows x 256 cols; W panel via 32KB LDS ping-pong.
// Lane layout fact: each lane's 64 acc values all belong to output row m = mbase+(lane&15);
// lanes {m, m+16, m+32, m+48} hold the full 256-dim row -> LN = shfl_xor(16)+shfl_xor(32).
__global__ __launch_bounds__(256) void bgemm_enc(const unsigned short* __restrict__ Xb,
                                                 const unsigned short* __restrict__ Wt,
                                                 const float* __restrict__ eb,
                                                 const float* __restrict__ gam,
                                                 const float* __restrict__ bet,
                                                 unsigned short* __restrict__ outp, int M) {
    __shared__ unsigned short Wl[2 * 16 * 64 * 8];   // 32 KB: 2 K-steps x 16 nf x 64 lanes x 16B
    int tid = threadIdx.x, wave = tid >> 6, lane = tid & 63;
    int lmod = lane & 15, ldiv = lane >> 4;
    int mbase = blockIdx.x * 64 + wave * 16;
    int row = min(mbase + lmod, M - 1);
    f32x4 acc[16] = {};
#pragma unroll
    for (int h = 0; h < 2; h++) {
        __syncthreads();   // protect buffer reuse
        for (int c = tid; c < 2048; c += 256) {
            int l = c & 63, nf = (c >> 6) & 15, kss = c >> 10;
            int n = nf * 16 + (l & 15);
            int k = (h * 2 + kss) * 32 + (l >> 4) * 8;
            *(bf16x8*)(Wl + (size_t)c * 8) = *(const bf16x8*)(Wt + (size_t)n * 128 + k);
        }
        __syncthreads();
#pragma unroll
        for (int kss = 0; kss < 2; kss++) {
            int ks = h * 2 + kss;
            bf16x8 xf = *(const bf16x8*)(Xb + (size_t)row * 128 + ks * 32 + ldiv * 8);
#pragma unroll
            for (int nf = 0; nf < 16; nf++) {
                bf16x8 wf = *(bf16x8*)(Wl + ((size_t)(kss * 16 + nf) * 64 + lane) * 8);
                acc[nf] = __builtin_amdgcn_mfma_f32_16x16x32_bf16(wf, xf, acc[nf], 0, 0, 0);
            }
        }
    }
    // epilogue: bias + LN + relu on row m = mbase + lmod
    float vs = 0.f;
#pragma unroll
    for (int nf = 0; nf < 16; nf++) {
        f4 bb = *(const f4*)(eb + nf * 16 + ldiv * 4);
#pragma unroll
        for (int r = 0; r < 4; r++) { acc[nf][r] += bb[r]; vs += acc[nf][r]; }
    }
    vs += __shfl_xor(vs, 16, 64); vs += __shfl_xor(vs, 32, 64);
    float mean = vs * (1.0f / 256.0f);
    float ss = 0.f;
#pragma unroll
    for (int nf = 0; nf < 16; nf++) {
#pragma unroll
        for (int r = 0; r < 4; r++) { float d = acc[nf][r] - mean; ss += d * d; }
    }
    ss += __shfl_xor(ss, 16, 64); ss += __shfl_xor(ss, 32, 64);
    float rs = rsqrtf(ss * (1.0f / 256.0f) + 1e-5f);
    int m = mbase + lmod;
    if (m < M) {
#pragma unroll
        for (int nf = 0; nf < 16; nf++) {
            f4 gv = *(const f4*)(gam + nf * 16 + ldiv * 4);
            f4 bv = *(const f4*)(bet + nf * 16 + ldiv * 4);
            u16x4 o;
#pragma unroll
            for (int r = 0; r < 4; r++)
                o[r] = f2b(fmaxf((acc[nf][r] - mean) * rs * gv[r] + bv[r], 0.0f));
            *(u16x4*)(outp + (size_t)m * 256 + nf * 16 + ldiv * 4) = o;
        }
    }
}

// ------------- GCN agg + bias + LN + relu (+ residual) (+ fused attention logit) -------------
__global__ void k_aggln(const unsigned short* __restrict__ T, const int* __restrict__ cnt,
                        const int* __restrict__ col,
                        const float* __restrict__ b, const float* __restrict__ gam,
                        const float* __restrict__ bet, const unsigned short* __restrict__ resid,
                        unsigned short* __restrict__ out,
                        const float* __restrict__ aw, const float* __restrict__ ab,
                        float* __restrict__ elog, int n) {
    int wid = (blockIdx.x * blockDim.x + threadIdx.x) >> 6;
    int lane = threadIdx.x & 63;
    if (wid >= n) return;
    int deg = min(cnt[wid], CSTRIDE);
    const int* cr = col + (size_t)wid * CSTRIDE;
    f4 a0 = {0.f,0.f,0.f,0.f}, a1 = {0.f,0.f,0.f,0.f};
    f4 a2 = {0.f,0.f,0.f,0.f}, a3 = {0.f,0.f,0.f,0.f};
    int e = 0;
    for (; e + 7 < deg; e += 8) {
        i32x4 cA = *(const i32x4*)(cr + e);
        i32x4 cB = *(const i32x4*)(cr + e + 4);
        u16x4 r0 = ((const u16x4*)(T + (size_t)cA[0] * HH))[lane];
        u16x4 r1 = ((const u16x4*)(T + (size_t)cA[1] * HH))[lane];
        u16x4 r2 = ((const u16x4*)(T + (size_t)cA[2] * HH))[lane];
        u16x4 r3 = ((const u16x4*)(T + (size_t)cA[3] * HH))[lane];
        u16x4 r4 = ((const u16x4*)(T + (size_t)cB[0] * HH))[lane];
        u16x4 r5 = ((const u16x4*)(T + (size_t)cB[1] * HH))[lane];
        u16x4 r6 = ((const u16x4*)(T + (size_t)cB[2] * HH))[lane];
        u16x4 r7 = ((const u16x4*)(T + (size_t)cB[3] * HH))[lane];
        float w0 = rsqrtf((float)(cnt[cA[0]] + 1));
        float w1 = rsqrtf((float)(cnt[cA[1]] + 1));
        float w2 = rsqrtf((float)(cnt[cA[2]] + 1));
        float w3 = rsqrtf((float)(cnt[cA[3]] + 1));
        float w4 = rsqrtf((float)(cnt[cB[0]] + 1));
        float w5 = rsqrtf((float)(cnt[cB[1]] + 1));
        float w6 = rsqrtf((float)(cnt[cB[2]] + 1));
        float w7 = rsqrtf((float)(cnt[cB[3]] + 1));
#pragma unroll
        for (int i = 0; i < 4; i++) {
            a0[i] = fmaf(w0, b2f(r0[i]), a0[i]);
            a1[i] = fmaf(w1, b2f(r1[i]), a1[i]);
            a2[i] = fmaf(w2, b2f(r2[i]), a2[i]);
            a3[i] = fmaf(w3, b2f(r3[i]), a3[i]);
            a0[i] = fmaf(w4, b2f(r4[i]), a0[i]);
            a1[i] = fmaf(w5, b2f(r5[i]), a1[i]);
            a2[i] = fmaf(w6, b2f(r6[i]), a2[i]);
            a3[i] = fmaf(w7, b2f(r7[i]), a3[i]);
        }
    }
    for (; e + 3 < deg; e += 4) {
        i32x4 c4 = *(const i32x4*)(cr + e);
        float w0 = rsqrtf((float)(cnt[c4[0]] + 1));
        float w1 = rsqrtf((float)(cnt[c4[1]] + 1));
        float w2 = rsqrtf((float)(cnt[c4[2]] + 1));
        float w3 = rsqrtf((float)(cnt[c4[3]] + 1));
        u16x4 r0 = ((const u16x4*)(T + (size_t)c4[0] * HH))[lane];
        u16x4 r1 = ((const u16x4*)(T + (size_t)c4[1] * HH))[lane];
        u16x4 r2 = ((const u16x4*)(T + (size_t)c4[2] * HH))[lane];
        u16x4 r3 = ((const u16x4*)(T + (size_t)c4[3] * HH))[lane];
#pragma unroll
        for (int i = 0; i < 4; i++) {
            a0[i] = fmaf(w0, b2f(r0[i]), a0[i]);
            a1[i] = fmaf(w1, b2f(r1[i]), a1[i]);
            a2[i] = fmaf(w2, b2f(r2[i]), a2[i]);
            a3[i] = fmaf(w3, b2f(r3[i]), a3[i]);
        }
    }
    for (; e < deg; e++) {
        int s0 = cr[e];
        float w0 = rsqrtf((float)(cnt[s0] + 1));
        u16x4 r0 = ((const u16x4*)(T + (size_t)s0 * HH))[lane];
#pragma unroll
        for (int i = 0; i < 4; i++) a0[i] = fmaf(w0, b2f(r0[i]), a0[i]);
    }
    float di = rsqrtf((float)(deg + 1));
    u16x4 sv = ((const u16x4*)(T + (size_t)wid * HH))[lane];
    f4 bb = ((const f4*)b)[lane];
    f4 v;
#pragma unroll
    for (int i = 0; i < 4; i++)
        v[i] = di * (a0[i] + a1[i] + a2[i] + a3[i]) + (di * di) * b2f(sv[i]) + bb[i];
    float s = wsum(v[0] + v[1] + v[2] + v[3]);
    float mean = s * (1.0f / HH);
    f4 d = v - mean;
    float ss = wsum(d[0] * d[0] + d[1] * d[1] + d[2] * d[2] + d[3] * d[3]);
    float rs = rsqrtf(ss * (1.0f / HH) + 1e-5f);
    f4 gv = ((const f4*)gam)[lane], bv = ((const f4*)bet)[lane];
    f4 o = d * rs * gv + bv;
#pragma unroll
    for (int i = 0; i < 4; i++) o[i] = fmaxf(o[i], 0.0f);
    if (resid != nullptr) {
        u16x4 rv = ((const u16x4*)(resid + (size_t)wid * HH))[lane];
#pragma unroll
        for (int i = 0; i < 4; i++) o[i] += b2f(rv[i]);
    }
    u16x4 ov;
#pragma unroll
    for (int i = 0; i < 4; i++) ov[i] = f2b(o[i]);
    ((u16x4*)(out + (size_t)wid * HH))[lane] = ov;
    if (elog != nullptr) {
        f4 wv = ((const f4*)aw)[lane];
        float dotv = wsum(b2f(ov[0]) * wv[0] + b2f(ov[1]) * wv[1] +
                          b2f(ov[2]) * wv[2] + b2f(ov[3]) * wv[3]);
        if (lane == 0) elog[wid] = expf(tanhf(dotv + ab[0]));
    }
}

// ---------------- pooling: partial weighted feature sums + partial elog sums ----------------
__device__ inline int lbound(const int* __restrict__ arr, int n, int key) {
    int lo = 0, hi = n;
    while (lo < hi) {
        int mid = (lo + hi) >> 1;
        if (arr[mid] < key) lo = mid + 1; else hi = mid;
    }
    return lo;
}

__global__ __launch_bounds__(256) void k_pool(const unsigned short* __restrict__ x3,
                                              const float* __restrict__ elog,
                                              const int* __restrict__ batch,
                                              float* __restrict__ partial,
                                              float* __restrict__ esum, int n) {
    int g = blockIdx.y, s = blockIdx.x, j = threadIdx.x;
    __shared__ int slo, shi;
    if (j == 0) { slo = lbound(batch, n, g); shi = lbound(batch, n, g + 1); }
    __syncthreads();
    int lo = slo, hi = shi;
    float a0 = 0.f, a1 = 0.f;
    int i = lo + s;
    for (; i + PSUB < hi; i += 2 * PSUB) {
        a0 += elog[i] * b2f(x3[(size_t)i * HH + j]);
        a1 += elog[i + PSUB] * b2f(x3[(size_t)(i + PSUB) * HH + j]);
    }
    if (i < hi) a0 += elog[i] * b2f(x3[(size_t)i * HH + j]);
    partial[(size_t)(g * PSUB + s) * HH + j] = a0 + a1;
    if (j < 64) {
        float es = 0.f;
        for (int t = j; (size_t)lo + s + (size_t)t * PSUB < (size_t)hi; t += 64)
            es += elog[lo + s + t * PSUB];
        es = wsum(es);
        if (j == 0) esum[g * PSUB + s] = es;
    }
}

// ---------------- tail: global elog sum + partial reduce + MLP + LN + project + L2 ----------------
__global__ __launch_bounds__(256) void k_tail(
    const float* __restrict__ partial, const float* __restrict__ esum,
    const float* __restrict__ pw1, const float* __restrict__ pb1,
    const float* __restrict__ pg, const float* __restrict__ pbe,
    const float* __restrict__ pw2, const float* __restrict__ pb2,
    float* __restrict__ out) {
    __shared__ float pl[256];
    __shared__ float ps[256];
    __shared__ float red[256];
    __shared__ float os[128];
    int g = blockIdx.x, j = threadIdx.x;
    float t = esum[j] + esum[j + 256] + esum[j + 512] + esum[j + 768];
    red[j] = t;
    __syncthreads();
    for (int s = 128; s > 0; s >>= 1) {
        if (j < s) red[j] += red[j + s];
        __syncthreads();
    }
    float inv = 1.0f / red[0];
    __syncthreads();
    float acc = 0.f;
#pragma unroll
    for (int s = 0; s < PSUB; s++) acc += partial[(size_t)(g * PSUB + s) * HH + j];
    pl[j] = acc * inv;
    __syncthreads();
    float q = pb1[j];
#pragma unroll 8
    for (int k = 0; k < 256; k++) q = fmaf(pl[k], pw1[k * 256 + j], q);
    red[j] = q;
    __syncthreads();
    for (int s = 128; s > 0; s >>= 1) {
        if (j < s) red[j] += red[j + s];
        __syncthreads();
    }
    float mean = red[0] * (1.0f / 256.0f);
    __syncthreads();
    float d = q - mean;
    red[j] = d * d;
    __syncthreads();
    for (int s = 128; s > 0; s >>= 1) {
        if (j < s) red[j] += red[j + s];
        __syncthreads();
    }
    float var = red[0] * (1.0f / 256.0f);
    __syncthreads();
    float p = fmaxf(d * rsqrtf(var + 1e-5f) * pg[j] + pbe[j], 0.0f);
    ps[j] = p;
    __syncthreads();
    if (j < 128) {
        float o = pb2[j];
#pragma unroll 8
        for (int k = 0; k < 256; k++) o = fmaf(ps[k], pw2[k * 128 + j], o);
        os[j] = o;
    }
    __syncthreads();
    float val = (j < 128) ? os[j] * os[j] : 0.f;
    red[j] = val;
    __syncthreads();
    for (int s = 128; s > 0; s >>= 1) {
        if (j < s) red[j] += red[j + s];
        __syncthreads();
    }
    float nrm = fmaxf(sqrtf(red[0]), 1e-12f);
    if (j < 128) out[g * 128 + j] = os[j] / nrm;
}

// ---------------- host ----------------
extern "C" void kernel_launch(void* const* d_in, const int* in_sizes, int n_in,
                              void* d_out, int out_size, void* d_ws, size_t ws_size,
                              hipStream_t stream) {
    const float* x      = (const float*)d_in[0];
    const int*   ei     = (const int*)d_in[1];
    const int*   batch  = (const int*)d_in[2];
    const float* enc_w  = (const float*)d_in[3];
    const float* enc_b  = (const float*)d_in[4];
    const float* enc_g  = (const float*)d_in[5];
    const float* enc_be = (const float*)d_in[6];
    const float* w1 = (const float*)d_in[7],  *b1 = (const float*)d_in[8];
    const float* g1 = (const float*)d_in[9],  *be1 = (const float*)d_in[10];
    const float* w2 = (const float*)d_in[11], *b2 = (const float*)d_in[12];
    const float* g2 = (const float*)d_in[13], *be2 = (const float*)d_in[14];
    const float* w3 = (const float*)d_in[15], *b3 = (const float*)d_in[16];
    const float* g3 = (const float*)d_in[17], *be3 = (const float*)d_in[18];
    const float* attn_w = (const float*)d_in[19], *attn_b = (const float*)d_in[20];
    const float* pw1 = (const float*)d_in[21], *pb1 = (const float*)d_in[22];
    const float* pg  = (const float*)d_in[23], *pbe = (const float*)d_in[24];
    const float* pw2 = (const float*)d_in[25], *pb2 = (const float*)d_in[26];
    float* out = (float*)d_out;

    const int* src = ei;
    const int* dst = ei + NEDGE;

    // bf16 region
    unsigned short* us = (unsigned short*)d_ws;
    unsigned short* Tb = us;                              // [NN,HH]
    unsigned short* Pb = Tb + (size_t)NN * HH;            // [NN,HH]
    unsigned short* Qb = Pb + (size_t)NN * HH;            // [NN,HH]
    unsigned short* xb = Qb + (size_t)NN * HH;            // [NN,FF]
    unsigned short* wte = xb + (size_t)NN * FF;           // [256*128]
    unsigned short* wt1 = wte + 256 * 128;                // [256*256]
    unsigned short* wt2 = wt1 + 256 * 256;
    unsigned short* wt3 = wt2 + 256 * 256;
    // fp32/int region (16B-aligned by construction)
    float* fp = (float*)(wt3 + 256 * 256);
    float* elog    = fp;                                  // [NN]
    float* partial = elog + NN;                           // [GG*PSUB*HH]
    float* esum    = partial + (size_t)GG * PSUB * HH;    // [GG*PSUB]
    int* cnt = (int*)(esum + GG * PSUB);                  // [NN]
    int* col = cnt + NN;                                  // [NN*CSTRIDE]

    // prep (also zeroes cnt) must complete before k_build's atomics
    k_prep<<<2576, 256, 0, stream>>>(x, xb, enc_w, w1, w2, w3, wte, wt1, wt2, wt3, cnt);
    k_build<<<(NEDGE + 255) / 256, 256, 0, stream>>>(src, dst, cnt, col, NEDGE);

    // fused encoder GEMM + bias + LN + relu -> Pb
    bgemm_enc<<<313, 256, 0, stream>>>(xb, wte, enc_b, enc_g, enc_be, Pb, NN);

    dim3 gg(4, 157);   // 628 blocks, 128-row tiles (LDS W panel, XCD remap)
    // layer 1: h=Pb -> T -> x1=Qb
    bgemm<256><<<gg, 256, 0, stream>>>(Pb, wt1, Tb, NN);
    k_aggln<<<(NN + 3) / 4, 256, 0, stream>>>(Tb, cnt, col, b1, g1, be1, nullptr, Qb,
                                              nullptr, nullptr, nullptr, NN);
    // layer 2: x1=Qb -> T -> x2=Pb (resid Qb)
    bgemm<256><<<gg, 256, 0, stream>>>(Qb, wt2, Tb, NN);
    k_aggln<<<(NN + 3) / 4, 256, 0, stream>>>(Tb, cnt, col, b2, g2, be2, Qb, Pb,
                                              nullptr, nullptr, nullptr, NN);
    // layer 3: x2=Pb -> T -> x3=Qb (resid Pb), fused attention logits
    bgemm<256><<<gg, 256, 0, stream>>>(Pb, wt3, Tb, NN);
    k_aggln<<<(NN + 3) / 4, 256, 0, stream>>>(Tb, cnt, col, b3, g3, be3, Pb, Qb,
                                              attn_w, attn_b, elog, NN);
    // pooling + tail
    k_pool<<<dim3(PSUB, GG), 256, 0, stream>>>(Qb, elog, batch, partial, esum, NN);
    k_tail<<<GG, 256, 0, stream>>>(partial, esum, pw1, pb1, pg, pbe, pw2, pb2, out);
}

// Round 9
// 195.873 us; speedup vs baseline: 1.1446x; 1.0563x over previous
//
#include <hip/hip_runtime.h>
#include <hip/hip_bf16.h>

#define NN 20000
#define FF 128
#define HH 256
#define EDIM 128
#define GG 64
#define NEDGE 320000
#define PSUB 16
#define CSTRIDE 64   // max in-degree slot count (mean 16, sigma 4 -> 64 is ~12 sigma)

typedef __attribute__((ext_vector_type(4))) float f4;
typedef __attribute__((ext_vector_type(4))) float f32x4;
typedef __attribute__((ext_vector_type(8))) short bf16x8;
typedef __attribute__((ext_vector_type(4))) unsigned short u16x4;
typedef __attribute__((ext_vector_type(4))) int i32x4;

__device__ inline float wsum(float v) {
#pragma unroll
    for (int m = 32; m >= 1; m >>= 1) v += __shfl_xor(v, m, 64);
    return v;
}

__device__ inline unsigned short f2b(float f) {
    union { float f; unsigned u; } x; x.f = f;
    unsigned r = x.u + 0x7fffu + ((x.u >> 16) & 1u);   // RNE
    return (unsigned short)(r >> 16);
}
__device__ inline float b2f(unsigned short u) {
    union { unsigned u; float f; } x; x.u = ((unsigned)u) << 16;
    return x.f;
}

// ---------------- prep: zero cnt (20), weight transpose via LDS (56) ----------------
// blocks [0,20): zero cnt; [20,28): enc wt (K=128); [28,44) w1; [44,60) w2; [60,76) w3
__global__ void k_prep(const float* __restrict__ W0, const float* __restrict__ W1,
                       const float* __restrict__ W2, const float* __restrict__ W3,
                       unsigned short* __restrict__ T0, unsigned short* __restrict__ T1,
                       unsigned short* __restrict__ T2, unsigned short* __restrict__ T3,
                       int* __restrict__ cnt) {
    int b = blockIdx.x, tid = threadIdx.x;
    if (b < 20) {
        int t = b * 256 + tid;
        if (t < NN / 4) ((i32x4*)cnt)[t] = (i32x4){0, 0, 0, 0};
        return;
    }
    const float* W; unsigned short* T; int K, tt;
    if (b < 28)      { W = W0; T = T0; K = 128; tt = b - 20; }
    else if (b < 44) { W = W1; T = T1; K = 256; tt = b - 28; }
    else if (b < 60) { W = W2; T = T2; K = 256; tt = b - 44; }
    else             { W = W3; T = T3; K = 256; tt = b - 60; }
    int ktiles = K / 64;
    int kt = tt % ktiles, nt = tt / ktiles;
    int k0 = kt * 64, n0 = nt * 64;
    __shared__ unsigned short ldsT[64][65];   // [n][k]
    int rn = (tid & 15) * 4, rk = tid >> 4;
#pragma unroll
    for (int i = 0; i < 4; i++) {
        int k = rk + 16 * i;
        f4 v = *(const f4*)(W + (size_t)(k0 + k) * 256 + n0 + rn);
#pragma unroll
        for (int j = 0; j < 4; j++) ldsT[rn + j][k] = f2b(v[j]);
    }
    __syncthreads();
    int wn = tid >> 2, kseg = (tid & 3) * 16;
#pragma unroll
    for (int q = 0; q < 4; q++) {
        u16x4 o = { ldsT[wn][kseg + q * 4 + 0], ldsT[wn][kseg + q * 4 + 1],
                    ldsT[wn][kseg + q * 4 + 2], ldsT[wn][kseg + q * 4 + 3] };
        *(u16x4*)(T + (size_t)(n0 + wn) * K + k0 + kseg + q * 4) = o;
    }
}

// ------- fused encoder (blocks [0,313)) + adjacency build (blocks [313,1563)) -------
// Encoder: h = relu(LN(x @ enc_w + b)); reads fp32 x, converts to bf16 in-register
// (bit-identical to pre-rounded path). 4 waves x 16 rows x 256 cols; 32KB LDS ping-pong.
// Lane layout: each lane's accs all belong to row m = mbase+(lane&15); lanes
// {m,m+16,m+32,m+48} hold the full row -> LN = shfl_xor(16)+shfl_xor(32).
__global__ __launch_bounds__(256) void k_encbuild(
        const float* __restrict__ X, const unsigned short* __restrict__ Wt,
        const float* __restrict__ eb, const float* __restrict__ gam,
        const float* __restrict__ bet, unsigned short* __restrict__ outp, int M,
        const int* __restrict__ src, const int* __restrict__ dst,
        int* __restrict__ cnt, int* __restrict__ colv, int ne) {
    __shared__ unsigned short Wl[2 * 16 * 64 * 8];   // 32 KB
    int b = blockIdx.x, tid = threadIdx.x;
    if (b >= 313) {   // ---- edge build ----
        int e = (b - 313) * 256 + tid;
        if (e < ne) {
            int d = dst[e];
            int pos = atomicAdd(&cnt[d], 1);
            if (pos < CSTRIDE) colv[(size_t)d * CSTRIDE + pos] = src[e];
        }
        return;
    }
    int wave = tid >> 6, lane = tid & 63;
    int lmod = lane & 15, ldiv = lane >> 4;
    int mbase = b * 64 + wave * 16;
    int row = min(mbase + lmod, M - 1);
    f32x4 acc[16] = {};
#pragma unroll
    for (int h = 0; h < 2; h++) {
        __syncthreads();
        for (int c = tid; c < 2048; c += 256) {
            int l = c & 63, nf = (c >> 6) & 15, kss = c >> 10;
            int n = nf * 16 + (l & 15);
            int k = (h * 2 + kss) * 32 + (l >> 4) * 8;
            *(bf16x8*)(Wl + (size_t)c * 8) = *(const bf16x8*)(Wt + (size_t)n * 128 + k);
        }
        __syncthreads();
#pragma unroll
        for (int kss = 0; kss < 2; kss++) {
            int ks = h * 2 + kss;
            f4 xa = *(const f4*)(X + (size_t)row * 128 + ks * 32 + ldiv * 8);
            f4 xb2 = *(const f4*)(X + (size_t)row * 128 + ks * 32 + ldiv * 8 + 4);
            bf16x8 xf;
            xf[0] = (short)f2b(xa[0]); xf[1] = (short)f2b(xa[1]);
            xf[2] = (short)f2b(xa[2]); xf[3] = (short)f2b(xa[3]);
            xf[4] = (short)f2b(xb2[0]); xf[5] = (short)f2b(xb2[1]);
            xf[6] = (short)f2b(xb2[2]); xf[7] = (short)f2b(xb2[3]);
#pragma unroll
            for (int nf = 0; nf < 16; nf++) {
                bf16x8 wf = *(bf16x8*)(Wl + ((size_t)(kss * 16 + nf) * 64 + lane) * 8);
                acc[nf] = __builtin_amdgcn_mfma_f32_16x16x32_bf16(wf, xf, acc[nf], 0, 0, 0);
            }
        }
    }
    float vs = 0.f;
#pragma unroll
    for (int nf = 0; nf < 16; nf++) {
        f4 bb = *(const f4*)(eb + nf * 16 + ldiv * 4);
#pragma unroll
        for (int r = 0; r < 4; r++) { acc[nf][r] += bb[r]; vs += acc[nf][r]; }
    }
    vs += __shfl_xor(vs, 16, 64); vs += __shfl_xor(vs, 32, 64);
    float mean = vs * (1.0f / 256.0f);
    float ss = 0.f;
#pragma unroll
    for (int nf = 0; nf < 16; nf++) {
#pragma unroll
        for (int r = 0; r < 4; r++) { float d = acc[nf][r] - mean; ss += d * d; }
    }
    ss += __shfl_xor(ss, 16, 64); ss += __shfl_xor(ss, 32, 64);
    float rs = rsqrtf(ss * (1.0f / 256.0f) + 1e-5f);
    int m = mbase + lmod;
    if (m < M) {
#pragma unroll
        for (int nf = 0; nf < 16; nf++) {
            f4 gv = *(const f4*)(gam + nf * 16 + ldiv * 4);
            f4 bv = *(const f4*)(bet + nf * 16 + ldiv * 4);
            u16x4 o;
#pragma unroll
            for (int r = 0; r < 4; r++)
                o[r] = f2b(fmaxf((acc[nf][r] - mean) * rs * gv[r] + bv[r], 0.0f));
            *(u16x4*)(outp + (size_t)m * 256 + nf * 16 + ldiv * 4) = o;
        }
    }
}

// ---------------- bf16 MFMA GEMM with LDS W panel (layers 1-3) ----------------
#define GEMM_NWG 628
template<int K>
__global__ __launch_bounds__(256) void bgemm(const unsigned short* __restrict__ Xb,
                                             const unsigned short* __restrict__ Wt,
                                             unsigned short* __restrict__ C, int M) {
    constexpr int KSTEPS = K / 32;
    __shared__ unsigned short Wl[KSTEPS * 4 * 64 * 8];
    int tid = threadIdx.x;
    int orig = blockIdx.y * 4 + blockIdx.x;
    int xcd = orig & 7, rest = orig >> 3;
    constexpr int q = GEMM_NWG >> 3, r = GEMM_NWG & 7;
    int wg = (xcd < r ? xcd * (q + 1) : r * (q + 1) + (xcd - r) * q) + rest;
    int m0 = wg >> 2;
    int n0 = (wg & 3) * 64;
    for (int c = tid; c < KSTEPS * 4 * 64; c += 256) {
        int lc = c & 63;
        int nf = (c >> 6) & 3;
        int ks = c >> 8;
        int n = n0 + nf * 16 + (lc & 15);
        int k = ks * 32 + (lc >> 4) * 8;
        bf16x8 v = *(const bf16x8*)(Wt + (size_t)n * K + k);
        *(bf16x8*)(Wl + (size_t)c * 8) = v;
    }
    __syncthreads();
    int wave = tid >> 6, lane = tid & 63;
    int lmod = lane & 15, ldiv = lane >> 4;
    int mbase = m0 * 128 + wave * 32;
    f32x4 acc[2][4] = {};
#pragma unroll
    for (int ks = 0; ks < KSTEPS; ks++) {
        int k0 = ks * 32 + ldiv * 8;
        bf16x8 xf[2], wf[4];
#pragma unroll
        for (int mf = 0; mf < 2; mf++) {
            int row = mbase + mf * 16 + lmod;
            row = min(row, M - 1);
            xf[mf] = *(const bf16x8*)(Xb + (size_t)row * K + k0);
        }
#pragma unroll
        for (int nf = 0; nf < 4; nf++) {
            wf[nf] = *(const bf16x8*)(Wl + ((size_t)(ks * 4 + nf) * 64 + lane) * 8);
        }
#pragma unroll
        for (int mf = 0; mf < 2; mf++) {
#pragma unroll
            for (int nf = 0; nf < 4; nf++) {
                acc[mf][nf] = __builtin_amdgcn_mfma_f32_16x16x32_bf16(
                    wf[nf], xf[mf], acc[mf][nf], 0, 0, 0);
            }
        }
    }
#pragma unroll
    for (int mf = 0; mf < 2; mf++) {
        int m = mbase + mf * 16 + lmod;
        if (m < M) {
#pragma unroll
            for (int nf = 0; nf < 4; nf++) {
                int n = n0 + nf * 16 + ldiv * 4;
                u16x4 o = { f2b(acc[mf][nf][0]), f2b(acc[mf][nf][1]),
                            f2b(acc[mf][nf][2]), f2b(acc[mf][nf][3]) };
                *(u16x4*)(C + (size_t)m * 256 + n) = o;
            }
        }
    }
}

// ------------- GCN agg + bias + LN + relu (+ residual) (+ fused attention logit) -------------
__global__ void k_aggln(const unsigned short* __restrict__ T, const int* __restrict__ cnt,
                        const int* __restrict__ col,
                        const float* __restrict__ b, const float* __restrict__ gam,
                        const float* __restrict__ bet, const unsigned short* __restrict__ resid,
                        unsigned short* __restrict__ out,
                        const float* __restrict__ aw, const float* __restrict__ ab,
                        float* __restrict__ elog, int n) {
    int wid = (blockIdx.x * blockDim.x + threadIdx.x) >> 6;
    int lane = threadIdx.x & 63;
    if (wid >= n) return;
    int deg = min(cnt[wid], CSTRIDE);
    const int* cr = col + (size_t)wid * CSTRIDE;
    f4 a0 = {0.f,0.f,0.f,0.f}, a1 = {0.f,0.f,0.f,0.f};
    f4 a2 = {0.f,0.f,0.f,0.f}, a3 = {0.f,0.f,0.f,0.f};
    int e = 0;
    for (; e + 7 < deg; e += 8) {
        i32x4 cA = *(const i32x4*)(cr + e);
        i32x4 cB = *(const i32x4*)(cr + e + 4);
        u16x4 r0 = ((const u16x4*)(T + (size_t)cA[0] * HH))[lane];
        u16x4 r1 = ((const u16x4*)(T + (size_t)cA[1] * HH))[lane];
        u16x4 r2 = ((const u16x4*)(T + (size_t)cA[2] * HH))[lane];
        u16x4 r3 = ((const u16x4*)(T + (size_t)cA[3] * HH))[lane];
        u16x4 r4 = ((const u16x4*)(T + (size_t)cB[0] * HH))[lane];
        u16x4 r5 = ((const u16x4*)(T + (size_t)cB[1] * HH))[lane];
        u16x4 r6 = ((const u16x4*)(T + (size_t)cB[2] * HH))[lane];
        u16x4 r7 = ((const u16x4*)(T + (size_t)cB[3] * HH))[lane];
        float w0 = rsqrtf((float)(cnt[cA[0]] + 1));
        float w1 = rsqrtf((float)(cnt[cA[1]] + 1));
        float w2 = rsqrtf((float)(cnt[cA[2]] + 1));
        float w3 = rsqrtf((float)(cnt[cA[3]] + 1));
        float w4 = rsqrtf((float)(cnt[cB[0]] + 1));
        float w5 = rsqrtf((float)(cnt[cB[1]] + 1));
        float w6 = rsqrtf((float)(cnt[cB[2]] + 1));
        float w7 = rsqrtf((float)(cnt[cB[3]] + 1));
#pragma unroll
        for (int i = 0; i < 4; i++) {
            a0[i] = fmaf(w0, b2f(r0[i]), a0[i]);
            a1[i] = fmaf(w1, b2f(r1[i]), a1[i]);
            a2[i] = fmaf(w2, b2f(r2[i]), a2[i]);
            a3[i] = fmaf(w3, b2f(r3[i]), a3[i]);
            a0[i] = fmaf(w4, b2f(r4[i]), a0[i]);
            a1[i] = fmaf(w5, b2f(r5[i]), a1[i]);
            a2[i] = fmaf(w6, b2f(r6[i]), a2[i]);
            a3[i] = fmaf(w7, b2f(r7[i]), a3[i]);
        }
    }
    for (; e + 3 < deg; e += 4) {
        i32x4 c4 = *(const i32x4*)(cr + e);
        float w0 = rsqrtf((float)(cnt[c4[0]] + 1));
        float w1 = rsqrtf((float)(cnt[c4[1]] + 1));
        float w2 = rsqrtf((float)(cnt[c4[2]] + 1));
        float w3 = rsqrtf((float)(cnt[c4[3]] + 1));
        u16x4 r0 = ((const u16x4*)(T + (size_t)c4[0] * HH))[lane];
        u16x4 r1 = ((const u16x4*)(T + (size_t)c4[1] * HH))[lane];
        u16x4 r2 = ((const u16x4*)(T + (size_t)c4[2] * HH))[lane];
        u16x4 r3 = ((const u16x4*)(T + (size_t)c4[3] * HH))[lane];
#pragma unroll
        for (int i = 0; i < 4; i++) {
            a0[i] = fmaf(w0, b2f(r0[i]), a0[i]);
            a1[i] = fmaf(w1, b2f(r1[i]), a1[i]);
            a2[i] = fmaf(w2, b2f(r2[i]), a2[i]);
            a3[i] = fmaf(w3, b2f(r3[i]), a3[i]);
        }
    }
    for (; e < deg; e++) {
        int s0 = cr[e];
        float w0 = rsqrtf((float)(cnt[s0] + 1));
        u16x4 r0 = ((const u16x4*)(T + (size_t)s0 * HH))[lane];
#pragma unroll
        for (int i = 0; i < 4; i++) a0[i] = fmaf(w0, b2f(r0[i]), a0[i]);
    }
    float di = rsqrtf((float)(deg + 1));
    u16x4 sv = ((const u16x4*)(T + (size_t)wid * HH))[lane];
    f4 bb = ((const f4*)b)[lane];
    f4 v;
#pragma unroll
    for (int i = 0; i < 4; i++)
        v[i] = di * (a0[i] + a1[i] + a2[i] + a3[i]) + (di * di) * b2f(sv[i]) + bb[i];
    float s = wsum(v[0] + v[1] + v[2] + v[3]);
    float mean = s * (1.0f / HH);
    f4 d = v - mean;
    float ss = wsum(d[0] * d[0] + d[1] * d[1] + d[2] * d[2] + d[3] * d[3]);
    float rs = rsqrtf(ss * (1.0f / HH) + 1e-5f);
    f4 gv = ((const f4*)gam)[lane], bv = ((const f4*)bet)[lane];
    f4 o = d * rs * gv + bv;
#pragma unroll
    for (int i = 0; i < 4; i++) o[i] = fmaxf(o[i], 0.0f);
    if (resid != nullptr) {
        u16x4 rv = ((const u16x4*)(resid + (size_t)wid * HH))[lane];
#pragma unroll
        for (int i = 0; i < 4; i++) o[i] += b2f(rv[i]);
    }
    u16x4 ov;
#pragma unroll
    for (int i = 0; i < 4; i++) ov[i] = f2b(o[i]);
    ((u16x4*)(out + (size_t)wid * HH))[lane] = ov;
    if (elog != nullptr) {
        f4 wv = ((const f4*)aw)[lane];
        float dotv = wsum(b2f(ov[0]) * wv[0] + b2f(ov[1]) * wv[1] +
                          b2f(ov[2]) * wv[2] + b2f(ov[3]) * wv[3]);
        if (lane == 0) elog[wid] = expf(tanhf(dotv + ab[0]));
    }
}

// ---------------- pooling: partial weighted feature sums + partial elog sums ----------------
__device__ inline int lbound(const int* __restrict__ arr, int n, int key) {
    int lo = 0, hi = n;
    while (lo < hi) {
        int mid = (lo + hi) >> 1;
        if (arr[mid] < key) lo = mid + 1; else hi = mid;
    }
    return lo;
}

__global__ __launch_bounds__(256) void k_pool(const unsigned short* __restrict__ x3,
                                              const float* __restrict__ elog,
                                              const int* __restrict__ batch,
                                              float* __restrict__ partial,
                                              float* __restrict__ esum, int n) {
    int g = blockIdx.y, s = blockIdx.x, j = threadIdx.x;
    __shared__ int slo, shi;
    if (j == 0) { slo = lbound(batch, n, g); shi = lbound(batch, n, g + 1); }
    __syncthreads();
    int lo = slo, hi = shi;
    float a0 = 0.f, a1 = 0.f;
    int i = lo + s;
    for (; i + PSUB < hi; i += 2 * PSUB) {
        a0 += elog[i] * b2f(x3[(size_t)i * HH + j]);
        a1 += elog[i + PSUB] * b2f(x3[(size_t)(i + PSUB) * HH + j]);
    }
    if (i < hi) a0 += elog[i] * b2f(x3[(size_t)i * HH + j]);
    partial[(size_t)(g * PSUB + s) * HH + j] = a0 + a1;
    if (j < 64) {
        float es = 0.f;
        for (int t = j; (size_t)lo + s + (size_t)t * PSUB < (size_t)hi; t += 64)
            es += elog[lo + s + t * PSUB];
        es = wsum(es);
        if (j == 0) esum[g * PSUB + s] = es;
    }
}

// ---------------- tail: global elog sum + partial reduce + MLP + LN + project + L2 ----------------
__global__ __launch_bounds__(256) void k_tail(
    const float* __restrict__ partial, const float* __restrict__ esum,
    const float* __restrict__ pw1, const float* __restrict__ pb1,
    const float* __restrict__ pg, const float* __restrict__ pbe,
    const float* __restrict__ pw2, const float* __restrict__ pb2,
    float* __restrict__ out) {
    __shared__ float pl[256];
    __shared__ float ps[256];
    __shared__ float red[256];
    __shared__ float os[128];
    int g = blockIdx.x, j = threadIdx.x;
    float t = esum[j] + esum[j + 256] + esum[j + 512] + esum[j + 768];
    red[j] = t;
    __syncthreads();
    for (int s = 128; s > 0; s >>= 1) {
        if (j < s) red[j] += red[j + s];
        __syncthreads();
    }
    float inv = 1.0f / red[0];
    __syncthreads();
    float acc = 0.f;
#pragma unroll
    for (int s = 0; s < PSUB; s++) acc += partial[(size_t)(g * PSUB + s) * HH + j];
    pl[j] = acc * inv;
    __syncthreads();
    float q = pb1[j];
#pragma unroll 8
    for (int k = 0; k < 256; k++) q = fmaf(pl[k], pw1[k * 256 + j], q);
    red[j] = q;
    __syncthreads();
    for (int s = 128; s > 0; s >>= 1) {
        if (j < s) red[j] += red[j + s];
        __syncthreads();
    }
    float mean = red[0] * (1.0f / 256.0f);
    __syncthreads();
    float d = q - mean;
    red[j] = d * d;
    __syncthreads();
    for (int s = 128; s > 0; s >>= 1) {
        if (j < s) red[j] += red[j + s];
        __syncthreads();
    }
    float var = red[0] * (1.0f / 256.0f);
    __syncthreads();
    float p = fmaxf(d * rsqrtf(var + 1e-5f) * pg[j] + pbe[j], 0.0f);
    ps[j] = p;
    __syncthreads();
    if (j < 128) {
        float o = pb2[j];
#pragma unroll 8
        for (int k = 0; k < 256; k++) o = fmaf(ps[k], pw2[k * 128 + j], o);
        os[j] = o;
    }
    __syncthreads();
    float val = (j < 128) ? os[j] * os[j] : 0.f;
    red[j] = val;
    __syncthreads();
    for (int s = 128; s > 0; s >>= 1) {
        if (j < s) red[j] += red[j + s];
        __syncthreads();
    }
    float nrm = fmaxf(sqrtf(red[0]), 1e-12f);
    if (j < 128) out[g * 128 + j] = os[j] / nrm;
}

// ---------------- host ----------------
extern "C" void kernel_launch(void* const* d_in, const int* in_sizes, int n_in,
                              void* d_out, int out_size, void* d_ws, size_t ws_size,
                              hipStream_t stream) {
    const float* x      = (const float*)d_in[0];
    const int*   ei     = (const int*)d_in[1];
    const int*   batch  = (const int*)d_in[2];
    const float* enc_w  = (const float*)d_in[3];
    const float* enc_b  = (const float*)d_in[4];
    const float* enc_g  = (const float*)d_in[5];
    const float* enc_be = (const float*)d_in[6];
    const float* w1 = (const float*)d_in[7],  *b1 = (const float*)d_in[8];
    const float* g1 = (const float*)d_in[9],  *be1 = (const float*)d_in[10];
    const float* w2 = (const float*)d_in[11], *b2 = (const float*)d_in[12];
    const float* g2 = (const float*)d_in[13], *be2 = (const float*)d_in[14];
    const float* w3 = (const float*)d_in[15], *b3 = (const float*)d_in[16];
    const float* g3 = (const float*)d_in[17], *be3 = (const float*)d_in[18];
    const float* attn_w = (const float*)d_in[19], *attn_b = (const float*)d_in[20];
    const float* pw1 = (const float*)d_in[21], *pb1 = (const float*)d_in[22];
    const float* pg  = (const float*)d_in[23], *pbe = (const float*)d_in[24];
    const float* pw2 = (const float*)d_in[25], *pb2 = (const float*)d_in[26];
    float* out = (float*)d_out;

    const int* src = ei;
    const int* dst = ei + NEDGE;

    // bf16 region
    unsigned short* us = (unsigned short*)d_ws;
    unsigned short* Tb = us;                              // [NN,HH]
    unsigned short* Pb = Tb + (size_t)NN * HH;            // [NN,HH]
    unsigned short* Qb = Pb + (size_t)NN * HH;            // [NN,HH]
    unsigned short* wte = Qb + (size_t)NN * HH;           // [256*128]
    unsigned short* wt1 = wte + 256 * 128;                // [256*256]
    unsigned short* wt2 = wt1 + 256 * 256;
    unsigned short* wt3 = wt2 + 256 * 256;
    // fp32/int region (16B-aligned by construction)
    float* fp = (float*)(wt3 + 256 * 256);
    float* elog    = fp;                                  // [NN]
    float* partial = elog + NN;                           // [GG*PSUB*HH]
    float* esum    = partial + (size_t)GG * PSUB * HH;    // [GG*PSUB]
    int* cnt = (int*)(esum + GG * PSUB);                  // [NN]
    int* col = cnt + NN;                                  // [NN*CSTRIDE]

    // prep: zero cnt + transpose weights (76 blocks)
    k_prep<<<76, 256, 0, stream>>>(enc_w, w1, w2, w3, wte, wt1, wt2, wt3, cnt);
    // fused encoder GEMM+LN (313 blocks) + edge build (1250 blocks)
    k_encbuild<<<313 + 1250, 256, 0, stream>>>(x, wte, enc_b, enc_g, enc_be, Pb, NN,
                                               src, dst, cnt, col, NEDGE);

    dim3 gg(4, 157);   // 628 blocks, 128-row tiles (LDS W panel, XCD remap)
    // layer 1: h=Pb -> T -> x1=Qb
    bgemm<256><<<gg, 256, 0, stream>>>(Pb, wt1, Tb, NN);
    k_aggln<<<(NN + 3) / 4, 256, 0, stream>>>(Tb, cnt, col, b1, g1, be1, nullptr, Qb,
                                              nullptr, nullptr, nullptr, NN);
    // layer 2: x1=Qb -> T -> x2=Pb (resid Qb)
    bgemm<256><<<gg, 256, 0, stream>>>(Qb, wt2, Tb, NN);
    k_aggln<<<(NN + 3) / 4, 256, 0, stream>>>(Tb, cnt, col, b2, g2, be2, Qb, Pb,
                                              nullptr, nullptr, nullptr, NN);
    // layer 3: x2=Pb -> T -> x3=Qb (resid Pb), fused attention logits
    bgemm<256><<<gg, 256, 0, stream>>>(Pb, wt3, Tb, NN);
    k_aggln<<<(NN + 3) / 4, 256, 0, stream>>>(Tb, cnt, col, b3, g3, be3, Pb, Qb,
                                              attn_w, attn_b, elog, NN);
    // pooling + tail
    k_pool<<<dim3(PSUB, GG), 256, 0, stream>>>(Qb, elog, batch, partial, esum, NN);
    k_tail<<<GG, 256, 0, stream>>>(partial, esum, pw1, pb1, pg, pbe, pw2, pb2, out);
}

// Round 10
// 183.579 us; speedup vs baseline: 1.2213x; 1.0670x over previous
//
#include <hip/hip_runtime.h>
#include <hip/hip_bf16.h>

#define NN 20000
#define FF 128
#define HH 256
#define EDIM 128
#define GG 64
#define NEDGE 320000
#define PSUB 16
#define CSTRIDE 64   // max in-degree slot count (mean 16, sigma 4 -> 64 is ~12 sigma)

typedef __attribute__((ext_vector_type(4))) float f4;
typedef __attribute__((ext_vector_type(4))) float f32x4;
typedef __attribute__((ext_vector_type(8))) short bf16x8;
typedef __attribute__((ext_vector_type(4))) unsigned short u16x4;
typedef __attribute__((ext_vector_type(4))) int i32x4;

__device__ inline float wsum(float v) {
#pragma unroll
    for (int m = 32; m >= 1; m >>= 1) v += __shfl_xor(v, m, 64);
    return v;
}

__device__ inline unsigned short f2b(float f) {
    union { float f; unsigned u; } x; x.f = f;
    unsigned r = x.u + 0x7fffu + ((x.u >> 16) & 1u);   // RNE
    return (unsigned short)(r >> 16);
}
__device__ inline float b2f(unsigned short u) {
    union { unsigned u; float f; } x; x.u = ((unsigned)u) << 16;
    return x.f;
}

// ---------------- prep: zero cnt (20), weight transpose via LDS (56) ----------------
__global__ void k_prep(const float* __restrict__ W0, const float* __restrict__ W1,
                       const float* __restrict__ W2, const float* __restrict__ W3,
                       unsigned short* __restrict__ T0, unsigned short* __restrict__ T1,
                       unsigned short* __restrict__ T2, unsigned short* __restrict__ T3,
                       int* __restrict__ cnt) {
    int b = blockIdx.x, tid = threadIdx.x;
    if (b < 20) {
        int t = b * 256 + tid;
        if (t < NN / 4) ((i32x4*)cnt)[t] = (i32x4){0, 0, 0, 0};
        return;
    }
    const float* W; unsigned short* T; int K, tt;
    if (b < 28)      { W = W0; T = T0; K = 128; tt = b - 20; }
    else if (b < 44) { W = W1; T = T1; K = 256; tt = b - 28; }
    else if (b < 60) { W = W2; T = T2; K = 256; tt = b - 44; }
    else             { W = W3; T = T3; K = 256; tt = b - 60; }
    int ktiles = K / 64;
    int kt = tt % ktiles, nt = tt / ktiles;
    int k0 = kt * 64, n0 = nt * 64;
    __shared__ unsigned short ldsT[64][65];   // [n][k]
    int rn = (tid & 15) * 4, rk = tid >> 4;
#pragma unroll
    for (int i = 0; i < 4; i++) {
        int k = rk + 16 * i;
        f4 v = *(const f4*)(W + (size_t)(k0 + k) * 256 + n0 + rn);
#pragma unroll
        for (int j = 0; j < 4; j++) ldsT[rn + j][k] = f2b(v[j]);
    }
    __syncthreads();
    int wn = tid >> 2, kseg = (tid & 3) * 16;
#pragma unroll
    for (int q = 0; q < 4; q++) {
        u16x4 o = { ldsT[wn][kseg + q * 4 + 0], ldsT[wn][kseg + q * 4 + 1],
                    ldsT[wn][kseg + q * 4 + 2], ldsT[wn][kseg + q * 4 + 3] };
        *(u16x4*)(T + (size_t)(n0 + wn) * K + k0 + kseg + q * 4) = o;
    }
}

// ------- fused encoder + GEMM1 (blocks [0,313)) + adjacency build ([313,1563)) -------
// Phase A: h = relu(LN(x @ enc_w + b)) for 64 rows, h kept in regs -> swizzled LDS.
// Phase B: T1 = h @ W1 straight from LDS h-tile + L2-resident W1. h never touches HBM.
__global__ __launch_bounds__(256) void k_encg1(
        const float* __restrict__ X, const unsigned short* __restrict__ Wt,
        const unsigned short* __restrict__ Wt1,
        const float* __restrict__ eb, const float* __restrict__ gam,
        const float* __restrict__ bet, unsigned short* __restrict__ T1out, int M,
        const int* __restrict__ src, const int* __restrict__ dst,
        int* __restrict__ cnt, int* __restrict__ colv, int ne) {
    __shared__ unsigned short Wl[2 * 16 * 64 * 8];   // 32 KB enc-W ping-pong
    __shared__ unsigned short hs[64 * 256];          // 32 KB h tile (XOR-swizzled rows)
    int b = blockIdx.x, tid = threadIdx.x;
    if (b >= 313) {   // ---- edge build ----
        int e = (b - 313) * 256 + tid;
        if (e < ne) {
            int d = dst[e];
            int pos = atomicAdd(&cnt[d], 1);
            if (pos < CSTRIDE) colv[(size_t)d * CSTRIDE + pos] = src[e];
        }
        return;
    }
    int wave = tid >> 6, lane = tid & 63;
    int lmod = lane & 15, ldiv = lane >> 4;
    int mbase = b * 64 + wave * 16;
    int row = min(mbase + lmod, M - 1);
    f32x4 acc[16] = {};
    // ---- phase A: encoder GEMM ----
#pragma unroll
    for (int h = 0; h < 2; h++) {
        __syncthreads();
        for (int c = tid; c < 2048; c += 256) {
            int l = c & 63, nf = (c >> 6) & 15, kss = c >> 10;
            int n = nf * 16 + (l & 15);
            int k = (h * 2 + kss) * 32 + (l >> 4) * 8;
            *(bf16x8*)(Wl + (size_t)c * 8) = *(const bf16x8*)(Wt + (size_t)n * 128 + k);
        }
        __syncthreads();
#pragma unroll
        for (int kss = 0; kss < 2; kss++) {
            int ks = h * 2 + kss;
            f4 xa = *(const f4*)(X + (size_t)row * 128 + ks * 32 + ldiv * 8);
            f4 xb2 = *(const f4*)(X + (size_t)row * 128 + ks * 32 + ldiv * 8 + 4);
            bf16x8 xf;
            xf[0] = (short)f2b(xa[0]); xf[1] = (short)f2b(xa[1]);
            xf[2] = (short)f2b(xa[2]); xf[3] = (short)f2b(xa[3]);
            xf[4] = (short)f2b(xb2[0]); xf[5] = (short)f2b(xb2[1]);
            xf[6] = (short)f2b(xb2[2]); xf[7] = (short)f2b(xb2[3]);
#pragma unroll
            for (int nf = 0; nf < 16; nf++) {
                bf16x8 wf = *(bf16x8*)(Wl + ((size_t)(kss * 16 + nf) * 64 + lane) * 8);
                acc[nf] = __builtin_amdgcn_mfma_f32_16x16x32_bf16(wf, xf, acc[nf], 0, 0, 0);
            }
        }
    }
    // bias + LN + relu; h row lives on lanes {m, m+16, m+32, m+48}
    float vs = 0.f;
#pragma unroll
    for (int nf = 0; nf < 16; nf++) {
        f4 bb = *(const f4*)(eb + nf * 16 + ldiv * 4);
#pragma unroll
        for (int r = 0; r < 4; r++) { acc[nf][r] += bb[r]; vs += acc[nf][r]; }
    }
    vs += __shfl_xor(vs, 16, 64); vs += __shfl_xor(vs, 32, 64);
    float mean = vs * (1.0f / 256.0f);
    float ss = 0.f;
#pragma unroll
    for (int nf = 0; nf < 16; nf++) {
#pragma unroll
        for (int r = 0; r < 4; r++) { float d = acc[nf][r] - mean; ss += d * d; }
    }
    ss += __shfl_xor(ss, 16, 64); ss += __shfl_xor(ss, 32, 64);
    float rs = rsqrtf(ss * (1.0f / 256.0f) + 1e-5f);
    // write h rows to swizzled LDS (bf16)
    int r_loc = wave * 16 + lmod;
    int swz = (r_loc & 7) << 4;
#pragma unroll
    for (int nf = 0; nf < 16; nf++) {
        f4 gv = *(const f4*)(gam + nf * 16 + ldiv * 4);
        f4 bv = *(const f4*)(bet + nf * 16 + ldiv * 4);
        u16x4 o;
#pragma unroll
        for (int r = 0; r < 4; r++)
            o[r] = f2b(fmaxf((acc[nf][r] - mean) * rs * gv[r] + bv[r], 0.0f));
        int byte = ((nf * 32 + ldiv * 8) ^ swz);
        *(u16x4*)((char*)hs + (size_t)r_loc * 512 + byte) = o;
    }
    __syncthreads();
    // ---- phase B: T1 = h @ W1 (wave covers all 64 rows x cols wave*64..+63) ----
    f32x4 acc2[4][4] = {};   // [row-group][nf]
    const unsigned short* wb = Wt1 + (size_t)(wave * 64 + lmod) * 256 + ldiv * 8;
#pragma unroll
    for (int ks = 0; ks < 8; ks++) {
        bf16x8 wf[4], hf[4];
#pragma unroll
        for (int nf = 0; nf < 4; nf++)
            wf[nf] = *(const bf16x8*)(wb + (size_t)nf * 16 * 256 + ks * 32);
#pragma unroll
        for (int rg = 0; rg < 4; rg++) {
            int rr = rg * 16 + lmod;
            int byte = ((ks * 64 + ldiv * 16) ^ ((rr & 7) << 4));
            hf[rg] = *(const bf16x8*)((const char*)hs + (size_t)rr * 512 + byte);
        }
#pragma unroll
        for (int rg = 0; rg < 4; rg++) {
#pragma unroll
            for (int nf = 0; nf < 4; nf++) {
                acc2[rg][nf] = __builtin_amdgcn_mfma_f32_16x16x32_bf16(
                    wf[nf], hf[rg], acc2[rg][nf], 0, 0, 0);
            }
        }
    }
#pragma unroll
    for (int rg = 0; rg < 4; rg++) {
        int m = b * 64 + rg * 16 + lmod;
        if (m < M) {
#pragma unroll
            for (int nf = 0; nf < 4; nf++) {
                int n = wave * 64 + nf * 16 + ldiv * 4;
                u16x4 o = { f2b(acc2[rg][nf][0]), f2b(acc2[rg][nf][1]),
                            f2b(acc2[rg][nf][2]), f2b(acc2[rg][nf][3]) };
                *(u16x4*)(T1out + (size_t)m * 256 + n) = o;
            }
        }
    }
}

// ---------------- bf16 MFMA GEMM with LDS W panel (layers 2-3) ----------------
#define GEMM_NWG 628
template<int K>
__global__ __launch_bounds__(256) void bgemm(const unsigned short* __restrict__ Xb,
                                             const unsigned short* __restrict__ Wt,
                                             unsigned short* __restrict__ C, int M) {
    constexpr int KSTEPS = K / 32;
    __shared__ unsigned short Wl[KSTEPS * 4 * 64 * 8];
    int tid = threadIdx.x;
    int orig = blockIdx.y * 4 + blockIdx.x;
    int xcd = orig & 7, rest = orig >> 3;
    constexpr int q = GEMM_NWG >> 3, r = GEMM_NWG & 7;
    int wg = (xcd < r ? xcd * (q + 1) : r * (q + 1) + (xcd - r) * q) + rest;
    int m0 = wg >> 2;
    int n0 = (wg & 3) * 64;
    for (int c = tid; c < KSTEPS * 4 * 64; c += 256) {
        int lc = c & 63;
        int nf = (c >> 6) & 3;
        int ks = c >> 8;
        int n = n0 + nf * 16 + (lc & 15);
        int k = ks * 32 + (lc >> 4) * 8;
        bf16x8 v = *(const bf16x8*)(Wt + (size_t)n * K + k);
        *(bf16x8*)(Wl + (size_t)c * 8) = v;
    }
    __syncthreads();
    int wave = tid >> 6, lane = tid & 63;
    int lmod = lane & 15, ldiv = lane >> 4;
    int mbase = m0 * 128 + wave * 32;
    f32x4 acc[2][4] = {};
#pragma unroll
    for (int ks = 0; ks < KSTEPS; ks++) {
        int k0 = ks * 32 + ldiv * 8;
        bf16x8 xf[2], wf[4];
#pragma unroll
        for (int mf = 0; mf < 2; mf++) {
            int row = mbase + mf * 16 + lmod;
            row = min(row, M - 1);
            xf[mf] = *(const bf16x8*)(Xb + (size_t)row * K + k0);
        }
#pragma unroll
        for (int nf = 0; nf < 4; nf++) {
            wf[nf] = *(const bf16x8*)(Wl + ((size_t)(ks * 4 + nf) * 64 + lane) * 8);
        }
#pragma unroll
        for (int mf = 0; mf < 2; mf++) {
#pragma unroll
            for (int nf = 0; nf < 4; nf++) {
                acc[mf][nf] = __builtin_amdgcn_mfma_f32_16x16x32_bf16(
                    wf[nf], xf[mf], acc[mf][nf], 0, 0, 0);
            }
        }
    }
#pragma unroll
    for (int mf = 0; mf < 2; mf++) {
        int m = mbase + mf * 16 + lmod;
        if (m < M) {
#pragma unroll
            for (int nf = 0; nf < 4; nf++) {
                int n = n0 + nf * 16 + ldiv * 4;
                u16x4 o = { f2b(acc[mf][nf][0]), f2b(acc[mf][nf][1]),
                            f2b(acc[mf][nf][2]), f2b(acc[mf][nf][3]) };
                *(u16x4*)(C + (size_t)m * 256 + n) = o;
            }
        }
    }
}

// ------------- GCN agg + bias + LN + relu (+ residual) (+ fused attention logit) -------------
__global__ void k_aggln(const unsigned short* __restrict__ T, const int* __restrict__ cnt,
                        const int* __restrict__ col,
                        const float* __restrict__ b, const float* __restrict__ gam,
                        const float* __restrict__ bet, const unsigned short* __restrict__ resid,
                        unsigned short* __restrict__ out,
                        const float* __restrict__ aw, const float* __restrict__ ab,
                        float* __restrict__ elog, int n) {
    int wid = (blockIdx.x * blockDim.x + threadIdx.x) >> 6;
    int lane = threadIdx.x & 63;
    if (wid >= n) return;
    int deg = min(cnt[wid], CSTRIDE);
    const int* cr = col + (size_t)wid * CSTRIDE;
    f4 a0 = {0.f,0.f,0.f,0.f}, a1 = {0.f,0.f,0.f,0.f};
    f4 a2 = {0.f,0.f,0.f,0.f}, a3 = {0.f,0.f,0.f,0.f};
    int e = 0;
    for (; e + 7 < deg; e += 8) {
        i32x4 cA = *(const i32x4*)(cr + e);
        i32x4 cB = *(const i32x4*)(cr + e + 4);
        u16x4 r0 = ((const u16x4*)(T + (size_t)cA[0] * HH))[lane];
        u16x4 r1 = ((const u16x4*)(T + (size_t)cA[1] * HH))[lane];
        u16x4 r2 = ((const u16x4*)(T + (size_t)cA[2] * HH))[lane];
        u16x4 r3 = ((const u16x4*)(T + (size_t)cA[3] * HH))[lane];
        u16x4 r4 = ((const u16x4*)(T + (size_t)cB[0] * HH))[lane];
        u16x4 r5 = ((const u16x4*)(T + (size_t)cB[1] * HH))[lane];
        u16x4 r6 = ((const u16x4*)(T + (size_t)cB[2] * HH))[lane];
        u16x4 r7 = ((const u16x4*)(T + (size_t)cB[3] * HH))[lane];
        float w0 = rsqrtf((float)(cnt[cA[0]] + 1));
        float w1 = rsqrtf((float)(cnt[cA[1]] + 1));
        float w2 = rsqrtf((float)(cnt[cA[2]] + 1));
        float w3 = rsqrtf((float)(cnt[cA[3]] + 1));
        float w4 = rsqrtf((float)(cnt[cB[0]] + 1));
        float w5 = rsqrtf((float)(cnt[cB[1]] + 1));
        float w6 = rsqrtf((float)(cnt[cB[2]] + 1));
        float w7 = rsqrtf((float)(cnt[cB[3]] + 1));
#pragma unroll
        for (int i = 0; i < 4; i++) {
            a0[i] = fmaf(w0, b2f(r0[i]), a0[i]);
            a1[i] = fmaf(w1, b2f(r1[i]), a1[i]);
            a2[i] = fmaf(w2, b2f(r2[i]), a2[i]);
            a3[i] = fmaf(w3, b2f(r3[i]), a3[i]);
            a0[i] = fmaf(w4, b2f(r4[i]), a0[i]);
            a1[i] = fmaf(w5, b2f(r5[i]), a1[i]);
            a2[i] = fmaf(w6, b2f(r6[i]), a2[i]);
            a3[i] = fmaf(w7, b2f(r7[i]), a3[i]);
        }
    }
    for (; e + 3 < deg; e += 4) {
        i32x4 c4 = *(const i32x4*)(cr + e);
        float w0 = rsqrtf((float)(cnt[c4[0]] + 1));
        float w1 = rsqrtf((float)(cnt[c4[1]] + 1));
        float w2 = rsqrtf((float)(cnt[c4[2]] + 1));
        float w3 = rsqrtf((float)(cnt[c4[3]] + 1));
        u16x4 r0 = ((const u16x4*)(T + (size_t)c4[0] * HH))[lane];
        u16x4 r1 = ((const u16x4*)(T + (size_t)c4[1] * HH))[lane];
        u16x4 r2 = ((const u16x4*)(T + (size_t)c4[2] * HH))[lane];
        u16x4 r3 = ((const u16x4*)(T + (size_t)c4[3] * HH))[lane];
#pragma unroll
        for (int i = 0; i < 4; i++) {
            a0[i] = fmaf(w0, b2f(r0[i]), a0[i]);
            a1[i] = fmaf(w1, b2f(r1[i]), a1[i]);
            a2[i] = fmaf(w2, b2f(r2[i]), a2[i]);
            a3[i] = fmaf(w3, b2f(r3[i]), a3[i]);
        }
    }
    for (; e < deg; e++) {
        int s0 = cr[e];
        float w0 = rsqrtf((float)(cnt[s0] + 1));
        u16x4 r0 = ((const u16x4*)(T + (size_t)s0 * HH))[lane];
#pragma unroll
        for (int i = 0; i < 4; i++) a0[i] = fmaf(w0, b2f(r0[i]), a0[i]);
    }
    float di = rsqrtf((float)(deg + 1));
    u16x4 sv = ((const u16x4*)(T + (size_t)wid * HH))[lane];
    f4 bb = ((const f4*)b)[lane];
    f4 v;
#pragma unroll
    for (int i = 0; i < 4; i++)
        v[i] = di * (a0[i] + a1[i] + a2[i] + a3[i]) + (di * di) * b2f(sv[i]) + bb[i];
    float s = wsum(v[0] + v[1] + v[2] + v[3]);
    float mean = s * (1.0f / HH);
    f4 d = v - mean;
    float ss = wsum(d[0] * d[0] + d[1] * d[1] + d[2] * d[2] + d[3] * d[3]);
    float rs = rsqrtf(ss * (1.0f / HH) + 1e-5f);
    f4 gv = ((const f4*)gam)[lane], bv = ((const f4*)bet)[lane];
    f4 o = d * rs * gv + bv;
#pragma unroll
    for (int i = 0; i < 4; i++) o[i] = fmaxf(o[i], 0.0f);
    if (resid != nullptr) {
        u16x4 rv = ((const u16x4*)(resid + (size_t)wid * HH))[lane];
#pragma unroll
        for (int i = 0; i < 4; i++) o[i] += b2f(rv[i]);
    }
    u16x4 ov;
#pragma unroll
    for (int i = 0; i < 4; i++) ov[i] = f2b(o[i]);
    ((u16x4*)(out + (size_t)wid * HH))[lane] = ov;
    if (elog != nullptr) {
        f4 wv = ((const f4*)aw)[lane];
        float dotv = wsum(b2f(ov[0]) * wv[0] + b2f(ov[1]) * wv[1] +
                          b2f(ov[2]) * wv[2] + b2f(ov[3]) * wv[3]);
        if (lane == 0) elog[wid] = expf(tanhf(dotv + ab[0]));
    }
}

// ---------------- pooling: partial weighted feature sums + partial elog sums ----------------
__device__ inline int lbound(const int* __restrict__ arr, int n, int key) {
    int lo = 0, hi = n;
    while (lo < hi) {
        int mid = (lo + hi) >> 1;
        if (arr[mid] < key) lo = mid + 1; else hi = mid;
    }
    return lo;
}

__global__ __launch_bounds__(256) void k_pool(const unsigned short* __restrict__ x3,
                                              const float* __restrict__ elog,
                                              const int* __restrict__ batch,
                                              float* __restrict__ partial,
                                              float* __restrict__ esum, int n) {
    int g = blockIdx.y, s = blockIdx.x, j = threadIdx.x;
    __shared__ int slo, shi;
    if (j == 0) { slo = lbound(batch, n, g); shi = lbound(batch, n, g + 1); }
    __syncthreads();
    int lo = slo, hi = shi;
    float a0 = 0.f, a1 = 0.f;
    int i = lo + s;
    for (; i + PSUB < hi; i += 2 * PSUB) {
        a0 += elog[i] * b2f(x3[(size_t)i * HH + j]);
        a1 += elog[i + PSUB] * b2f(x3[(size_t)(i + PSUB) * HH + j]);
    }
    if (i < hi) a0 += elog[i] * b2f(x3[(size_t)i * HH + j]);
    partial[(size_t)(g * PSUB + s) * HH + j] = a0 + a1;
    if (j < 64) {
        float es = 0.f;
        for (int t = j; (size_t)lo + s + (size_t)t * PSUB < (size_t)hi; t += 64)
            es += elog[lo + s + t * PSUB];
        es = wsum(es);
        if (j == 0) esum[g * PSUB + s] = es;
    }
}

// ---------------- tail: global elog sum + partial reduce + MLP + LN + project + L2 ----------------
__global__ __launch_bounds__(256) void k_tail(
    const float* __restrict__ partial, const float* __restrict__ esum,
    const float* __restrict__ pw1, const float* __restrict__ pb1,
    const float* __restrict__ pg, const float* __restrict__ pbe,
    const float* __restrict__ pw2, const float* __restrict__ pb2,
    float* __restrict__ out) {
    __shared__ float pl[256];
    __shared__ float ps[256];
    __shared__ float red[256];
    __shared__ float os[128];
    int g = blockIdx.x, j = threadIdx.x;
    float t = esum[j] + esum[j + 256] + esum[j + 512] + esum[j + 768];
    red[j] = t;
    __syncthreads();
    for (int s = 128; s > 0; s >>= 1) {
        if (j < s) red[j] += red[j + s];
        __syncthreads();
    }
    float inv = 1.0f / red[0];
    __syncthreads();
    float acc = 0.f;
#pragma unroll
    for (int s = 0; s < PSUB; s++) acc += partial[(size_t)(g * PSUB + s) * HH + j];
    pl[j] = acc * inv;
    __syncthreads();
    float q = pb1[j];
#pragma unroll 8
    for (int k = 0; k < 256; k++) q = fmaf(pl[k], pw1[k * 256 + j], q);
    red[j] = q;
    __syncthreads();
    for (int s = 128; s > 0; s >>= 1) {
        if (j < s) red[j] += red[j + s];
        __syncthreads();
    }
    float mean = red[0] * (1.0f / 256.0f);
    __syncthreads();
    float d = q - mean;
    red[j] = d * d;
    __syncthreads();
    for (int s = 128; s > 0; s >>= 1) {
        if (j < s) red[j] += red[j + s];
        __syncthreads();
    }
    float var = red[0] * (1.0f / 256.0f);
    __syncthreads();
    float p = fmaxf(d * rsqrtf(var + 1e-5f) * pg[j] + pbe[j], 0.0f);
    ps[j] = p;
    __syncthreads();
    if (j < 128) {
        float o = pb2[j];
#pragma unroll 8
        for (int k = 0; k < 256; k++) o = fmaf(ps[k], pw2[k * 128 + j], o);
        os[j] = o;
    }
    __syncthreads();
    float val = (j < 128) ? os[j] * os[j] : 0.f;
    red[j] = val;
    __syncthreads();
    for (int s = 128; s > 0; s >>= 1) {
        if (j < s) red[j] += red[j + s];
        __syncthreads();
    }
    float nrm = fmaxf(sqrtf(red[0]), 1e-12f);
    if (j < 128) out[g * 128 + j] = os[j] / nrm;
}

// ---------------- host ----------------
extern "C" void kernel_launch(void* const* d_in, const int* in_sizes, int n_in,
                              void* d_out, int out_size, void* d_ws, size_t ws_size,
                              hipStream_t stream) {
    const float* x      = (const float*)d_in[0];
    const int*   ei     = (const int*)d_in[1];
    const int*   batch  = (const int*)d_in[2];
    const float* enc_w  = (const float*)d_in[3];
    const float* enc_b  = (const float*)d_in[4];
    const float* enc_g  = (const float*)d_in[5];
    const float* enc_be = (const float*)d_in[6];
    const float* w1 = (const float*)d_in[7],  *b1 = (const float*)d_in[8];
    const float* g1 = (const float*)d_in[9],  *be1 = (const float*)d_in[10];
    const float* w2 = (const float*)d_in[11], *b2 = (const float*)d_in[12];
    const float* g2 = (const float*)d_in[13], *be2 = (const float*)d_in[14];
    const float* w3 = (const float*)d_in[15], *b3 = (const float*)d_in[16];
    const float* g3 = (const float*)d_in[17], *be3 = (const float*)d_in[18];
    const float* attn_w = (const float*)d_in[19], *attn_b = (const float*)d_in[20];
    const float* pw1 = (const float*)d_in[21], *pb1 = (const float*)d_in[22];
    const float* pg  = (const float*)d_in[23], *pbe = (const float*)d_in[24];
    const float* pw2 = (const float*)d_in[25], *pb2 = (const float*)d_in[26];
    float* out = (float*)d_out;

    const int* src = ei;
    const int* dst = ei + NEDGE;

    // bf16 region
    unsigned short* us = (unsigned short*)d_ws;
    unsigned short* Tb = us;                              // [NN,HH]
    unsigned short* Pb = Tb + (size_t)NN * HH;            // [NN,HH] (x2)
    unsigned short* Qb = Pb + (size_t)NN * HH;            // [NN,HH] (x1, then x3)
    unsigned short* wte = Qb + (size_t)NN * HH;           // [256*128]
    unsigned short* wt1 = wte + 256 * 128;                // [256*256]
    unsigned short* wt2 = wt1 + 256 * 256;
    unsigned short* wt3 = wt2 + 256 * 256;
    // fp32/int region (16B-aligned by construction)
    float* fp = (float*)(wt3 + 256 * 256);
    float* elog    = fp;                                  // [NN]
    float* partial = elog + NN;                           // [GG*PSUB*HH]
    float* esum    = partial + (size_t)GG * PSUB * HH;    // [GG*PSUB]
    int* cnt = (int*)(esum + GG * PSUB);                  // [NN]
    int* col = cnt + NN;                                  // [NN*CSTRIDE]

    // prep: zero cnt + transpose weights (76 blocks)
    k_prep<<<76, 256, 0, stream>>>(enc_w, w1, w2, w3, wte, wt1, wt2, wt3, cnt);
    // fused encoder GEMM+LN+GEMM1 -> T1 (313 blocks) + edge build (1250 blocks)
    k_encg1<<<313 + 1250, 256, 0, stream>>>(x, wte, wt1, enc_b, enc_g, enc_be, Tb, NN,
                                            src, dst, cnt, col, NEDGE);

    dim3 gg(4, 157);   // 628 blocks, 128-row tiles (LDS W panel, XCD remap)
    // layer 1: T1=Tb -> x1=Qb
    k_aggln<<<(NN + 3) / 4, 256, 0, stream>>>(Tb, cnt, col, b1, g1, be1, nullptr, Qb,
                                              nullptr, nullptr, nullptr, NN);
    // layer 2: x1=Qb -> T2=Tb -> x2=Pb (resid Qb)
    bgemm<256><<<gg, 256, 0, stream>>>(Qb, wt2, Tb, NN);
    k_aggln<<<(NN + 3) / 4, 256, 0, stream>>>(Tb, cnt, col, b2, g2, be2, Qb, Pb,
                                              nullptr, nullptr, nullptr, NN);
    // layer 3: x2=Pb -> T3=Tb -> x3=Qb (resid Pb), fused attention logits
    bgemm<256><<<gg, 256, 0, stream>>>(Pb, wt3, Tb, NN);
    k_aggln<<<(NN + 3) / 4, 256, 0, stream>>>(Tb, cnt, col, b3, g3, be3, Pb, Qb,
                                              attn_w, attn_b, elog, NN);
    // pooling + tail
    k_pool<<<dim3(PSUB, GG), 256, 0, stream>>>(Qb, elog, batch, partial, esum, NN);
    k_tail<<<GG, 256, 0, stream>>>(partial, esum, pw1, pb1, pg, pbe, pw2, pb2, out);
}